// Round 17
// baseline (141.844 us; speedup 1.0000x reference)
//
#include <hip/hip_runtime.h>
#include <hip/hip_bf16.h>

#define S_LEN 4096
#define NEG_INF_F (-1e30f)

typedef __attribute__((ext_vector_type(4))) float f32x4;
typedef __attribute__((ext_vector_type(8))) short s16x8;
typedef unsigned short u16;

static __device__ __forceinline__ u16 f2bf(float f) {
    unsigned u = __builtin_bit_cast(unsigned, f);
    unsigned r = u + 0x7FFFu + ((u >> 16) & 1u);
    return (u16)(r >> 16);
}
static __device__ __forceinline__ float bf2f(u16 h) {
    unsigned u = ((unsigned)h) << 16;
    return __builtin_bit_cast(float, u);
}
static __device__ __forceinline__ void split4(const float4 v, ushort4& hi, ushort4& lo) {
    hi.x = f2bf(v.x); lo.x = f2bf(v.x - bf2f(hi.x));
    hi.y = f2bf(v.y); lo.y = f2bf(v.y - bf2f(hi.y));
    hi.z = f2bf(v.z); lo.z = f2bf(v.z - bf2f(hi.z));
    hi.w = f2bf(v.w); lo.w = f2bf(v.w - bf2f(hi.w));
}
static __device__ __forceinline__ void gl_lds16(const void* g, void* l) {
    __builtin_amdgcn_global_load_lds(
        (const __attribute__((address_space(1))) void*)g,
        (__attribute__((address_space(3))) void*)l, 16, 0, 0);
}
// swizzled u16 offset within a [rows][64 u16] LDS tile
static __device__ __forceinline__ int swz64(int row, int col_u16) {
    return row * 64 + (col_u16 ^ ((row & 7) << 3));
}
// swizzled u16 offset within a [rows][32 u16] LDS tile
static __device__ __forceinline__ int swz32(int row, int col_u16) {
    return row * 32 + (col_u16 ^ (((row >> 1) & 3) << 3));
}
// swizzled u16 offset within a [rows][320 u16] LDS tile
static __device__ __forceinline__ int swz320(int row, int col_u16) {
    return row * 320 + (col_u16 ^ ((row & 7) << 3));
}
// XCD-chunked bijective swizzles
static __device__ __forceinline__ int xcd_swz512(int bid) {
    return (bid & 7) * 64 + (bid >> 3);
}
static __device__ __forceinline__ int xcd_swz256(int bid) {
    return (bid & 7) * 32 + (bid >> 3);
}

// ---------------- K0: split x -> xh, xl AND xT (fused transpose) ----------------
__global__ __launch_bounds__(256) void split_xt_kernel(
    const float* __restrict__ x, u16* __restrict__ xh, u16* __restrict__ xl,
    u16* __restrict__ xT) {
    const int bid = blockIdx.x;
    const int dt = bid & 7, st = (bid >> 3) & 63, b = bid >> 9;
    const int s0 = st * 64, d0 = dt * 64;
    __shared__ u16 T[64][72];
    const int tid = threadIdx.x;
    #pragma unroll
    for (int i = 0; i < 4; ++i) {
        int idx = i * 256 + tid;
        int r = idx >> 4, c4 = (idx & 15) * 4;
        float4 v = *(const float4*)(x + (size_t)(b * S_LEN + s0 + r) * 512 + d0 + c4);
        ushort4 hi, lo; split4(v, hi, lo);
        *(ushort4*)(xh + (size_t)(b * S_LEN + s0 + r) * 512 + d0 + c4) = hi;
        *(ushort4*)(xl + (size_t)(b * S_LEN + s0 + r) * 512 + d0 + c4) = lo;
        *(ushort4*)&T[r][c4] = hi;
    }
    __syncthreads();
    #pragma unroll
    for (int i = 0; i < 2; ++i) {
        int idx = i * 256 + tid;
        int dr = idx >> 3, sc = idx & 7;
        s16x8 v;
        #pragma unroll
        for (int t = 0; t < 8; ++t) v[t] = (short)T[sc * 8 + t][dr];
        *(s16x8*)&xT[(size_t)(b * 512 + d0 + dr) * S_LEN + s0 + sc * 8] = v;
    }
}

// ---------------- K1: Mt = Wk^T @ Wq (32x32 tiles, grid 256) ----------------
__global__ __launch_bounds__(256) void mt_kernel(
    const float* __restrict__ Wk, const float* __restrict__ Wq,
    u16* __restrict__ Mth, u16* __restrict__ Mtl) {
    const int bm = blockIdx.x & 15, bn = blockIdx.x >> 4;
    const int m0 = bm * 32, n0 = bn * 32;
    __shared__ __align__(16) u16 Ath[32 * 72], Atl[32 * 72];
    __shared__ __align__(16) u16 Bth[32 * 72], Btl[32 * 72];
    const int tid = threadIdx.x, lane = tid & 63, w = tid >> 6;
    const int rg = w >> 1, cg = w & 1;
    const int frow = lane & 15, fk = (lane >> 4) * 8;
    f32x4 acc = {};

    for (int h0 = 0; h0 < 512; h0 += 64) {
        #pragma unroll
        for (int i = 0; i < 2; ++i) {
            int idx = i * 256 + tid;           // 512 slots: 64 h x 8 c4
            int h = idx >> 3, c4 = (idx & 7) * 4;
            float4 a = *(const float4*)(Wk + (size_t)(h0 + h) * 512 + m0 + c4);
            ushort4 ahi, alo; split4(a, ahi, alo);
            Ath[(c4 + 0) * 72 + h] = ahi.x; Atl[(c4 + 0) * 72 + h] = alo.x;
            Ath[(c4 + 1) * 72 + h] = ahi.y; Atl[(c4 + 1) * 72 + h] = alo.y;
            Ath[(c4 + 2) * 72 + h] = ahi.z; Atl[(c4 + 2) * 72 + h] = alo.z;
            Ath[(c4 + 3) * 72 + h] = ahi.w; Atl[(c4 + 3) * 72 + h] = alo.w;
            float4 b = *(const float4*)(Wq + (size_t)(h0 + h) * 512 + n0 + c4);
            ushort4 bhi, blo; split4(b, bhi, blo);
            Bth[(c4 + 0) * 72 + h] = bhi.x; Btl[(c4 + 0) * 72 + h] = blo.x;
            Bth[(c4 + 1) * 72 + h] = bhi.y; Btl[(c4 + 1) * 72 + h] = blo.y;
            Bth[(c4 + 2) * 72 + h] = bhi.z; Btl[(c4 + 2) * 72 + h] = blo.z;
            Bth[(c4 + 3) * 72 + h] = bhi.w; Btl[(c4 + 3) * 72 + h] = blo.w;
        }
        __syncthreads();
        #pragma unroll
        for (int kk = 0; kk < 2; ++kk) {
            s16x8 aH = *(const s16x8*)&Ath[(rg * 16 + frow) * 72 + kk * 32 + fk];
            s16x8 aL = *(const s16x8*)&Atl[(rg * 16 + frow) * 72 + kk * 32 + fk];
            s16x8 bH = *(const s16x8*)&Bth[(cg * 16 + frow) * 72 + kk * 32 + fk];
            s16x8 bL = *(const s16x8*)&Btl[(cg * 16 + frow) * 72 + kk * 32 + fk];
            acc = __builtin_amdgcn_mfma_f32_16x16x32_bf16(aH, bH, acc, 0, 0, 0);
            acc = __builtin_amdgcn_mfma_f32_16x16x32_bf16(aH, bL, acc, 0, 0, 0);
            acc = __builtin_amdgcn_mfma_f32_16x16x32_bf16(aL, bH, acc, 0, 0, 0);
        }
        __syncthreads();
    }
    {
        int d1 = n0 + cg * 16 + frow;
        #pragma unroll
        for (int e = 0; e < 4; ++e) {
            int d2 = m0 + rg * 16 + (lane >> 4) * 4 + e;
            float v = acc[e];
            u16 hi = f2bf(v);
            Mth[(size_t)d2 * 512 + d1] = hi;
            Mtl[(size_t)d2 * 512 + d1] = f2bf(v - bf2f(hi));
        }
    }
}

// ---------------- K2: u = Wk^T @ bq ----------------
__global__ __launch_bounds__(256) void u_kernel(
    const float* __restrict__ Wk, const float* __restrict__ bq,
    float* __restrict__ u) {
    __shared__ float red[4][64];
    const int tid = threadIdx.x, c = tid & 63, hg = tid >> 6;
    const int d2 = blockIdx.x * 64 + c;
    float acc = 0.f;
    for (int h = hg; h < 512; h += 4) acc += Wk[(size_t)h * 512 + d2] * bq[h];
    red[hg][c] = acc;
    __syncthreads();
    if (hg == 0) u[d2] = red[0][c] + red[1][c] + red[2][c] + red[3][c];
}

// ---------------- K3: z = x @ Mt^T + u (reg-staged, BK=32, kr[4]) ----------------
// grid 512 = 128 m-tiles x 4 n-tiles (XCD-swizzled). block 512 (8 waves: 2 rg x 4 cg).
// Staging global->reg->ds_write with the PROVEN round-13 footprint: 4 chunks/thread
// (16 VGPR), single 32KB buffer, {bar; kwrite; bar; kload(t+1); MFMA} per step.
__global__ __launch_bounds__(512, 4) void z_kernel(
    const u16* __restrict__ xh, const u16* __restrict__ xl,
    const u16* __restrict__ Mth, const u16* __restrict__ Mtl,
    const float* __restrict__ u, u16* __restrict__ zh, u16* __restrict__ zl) {
    const int w_ = xcd_swz512((int)blockIdx.x);
    const int bm = w_ >> 2, bn = w_ & 3;
    const int m0 = bm * 128, n0 = bn * 128;
    __shared__ __align__(16) u16 smz[16384];   // 32KB: arrays {Ah,Al,Bh,Bl} x [128][32]
    const int tid = threadIdx.x, lane = tid & 63, w = tid >> 6;
    const int rg = w >> 2, cg = w & 3;
    const int frow = lane & 15, fk = (lane >> 4) * 8;
    f32x4 acc[4][2] = {};
    s16x8 kr[4];

    auto kload = [&](int t) {
        const int k0 = t * 32;
        #pragma unroll
        for (int i = 0; i < 4; ++i) {
            int f = i * 512 + tid;               // 2048 chunks: 4 arrays x 512
            int a = f >> 9, idx = f & 511;
            int r = idx >> 2, c = idx & 3;
            const u16* src = (a == 0) ? xh : (a == 1) ? xl : (a == 2) ? Mth : Mtl;
            const int row0 = (a < 2) ? m0 : n0;
            kr[i] = *(const s16x8*)(src + (size_t)(row0 + r) * 512 + k0 + c * 8);
        }
    };
    auto kwrite = [&]() {
        #pragma unroll
        for (int i = 0; i < 4; ++i) {
            int f = i * 512 + tid;
            int a = f >> 9, idx = f & 511;
            int r = idx >> 2, c = idx & 3;
            *(s16x8*)&smz[a * 4096 + swz32(r, c * 8)] = kr[i];
        }
    };

    kload(0);
    for (int t = 0; t < 16; ++t) {
        __syncthreads();                 // prev step's LDS reads done
        kwrite();
        __syncthreads();                 // tile visible
        if (t < 15) kload(t + 1);        // flies under this step's MFMA
        s16x8 aH[4], aL[4];
        #pragma unroll
        for (int mi = 0; mi < 4; ++mi) {
            int row = rg * 64 + mi * 16 + frow;
            aH[mi] = *(const s16x8*)&smz[0 * 4096 + swz32(row, fk)];
            aL[mi] = *(const s16x8*)&smz[1 * 4096 + swz32(row, fk)];
        }
        __builtin_amdgcn_s_setprio(1);
        #pragma unroll
        for (int ni = 0; ni < 2; ++ni) {
            int row = cg * 32 + ni * 16 + frow;
            s16x8 bH = *(const s16x8*)&smz[2 * 4096 + swz32(row, fk)];
            s16x8 bL = *(const s16x8*)&smz[3 * 4096 + swz32(row, fk)];
            #pragma unroll
            for (int mi = 0; mi < 4; ++mi) {
                acc[mi][ni] = __builtin_amdgcn_mfma_f32_16x16x32_bf16(aH[mi], bH, acc[mi][ni], 0, 0, 0);
                acc[mi][ni] = __builtin_amdgcn_mfma_f32_16x16x32_bf16(aH[mi], bL, acc[mi][ni], 0, 0, 0);
                acc[mi][ni] = __builtin_amdgcn_mfma_f32_16x16x32_bf16(aL[mi], bH, acc[mi][ni], 0, 0, 0);
            }
        }
        __builtin_amdgcn_s_setprio(0);
    }
    #pragma unroll
    for (int ni = 0; ni < 2; ++ni) {
        int col = n0 + cg * 32 + ni * 16 + frow;
        float uv = u[col];
        #pragma unroll
        for (int mi = 0; mi < 4; ++mi) {
            int rbase = m0 + rg * 64 + mi * 16 + (lane >> 4) * 4;
            #pragma unroll
            for (int e = 0; e < 4; ++e) {
                float v = acc[mi][ni][e] + uv;
                u16 hi = f2bf(v);
                zh[(size_t)(rbase + e) * 512 + col] = hi;
                zl[(size_t)(rbase + e) * 512 + col] = f2bf(v - bf2f(hi));
            }
        }
    }
}

// ---------------- K4: fused banded attention, 64-row tiles, reg-staged ----------------
// (round-13 version: 48.6us, VGPR 44, zero bank conflicts)
__global__ __launch_bounds__(1024, 4) void attn_kernel(
    const u16* __restrict__ zh, const u16* __restrict__ zl,
    const u16* __restrict__ xh, const u16* __restrict__ xl,
    const u16* __restrict__ xT, float* __restrict__ out) {
    const int w_ = xcd_swz256((int)blockIdx.x);
    const int b = w_ >> 6, it = w_ & 63;
    const int i0 = it * 64, j0 = i0 - 128;
    const int mrow0 = b * S_LEN + i0;

    __shared__ __align__(16) u16 smem[40960];        // 80 KB

    const int tid = threadIdx.x, lane = tid & 63, w = tid >> 6;
    const int g = w >> 2, q = w & 3;
    const int frow = lane & 15, fk = (lane >> 4) * 8;
    const int tstart = g + q * 4;
    const int nt = (q == 3) ? 5 : 4;
    const size_t qoff = (size_t)(mrow0 + g * 16 + frow) * 512;
    const int rq = (lane >> 4) * 4;

    f32x4 acc[5] = {};
    s16x8 krA[3], krB[3];

    auto kload = [&](int s, s16x8* kr) {
        const int k0 = s * 32;
        #pragma unroll
        for (int i = 0; i < 3; ++i) {
            int f = i * 1024 + tid;
            if (f < 2560) {
                int idx = (f < 1280) ? f : f - 1280;
                int r = idx >> 2, c = idx & 3;
                int j = min(max(j0 + r, 0), S_LEN - 1);
                const u16* src = (f < 1280) ? xh : xl;
                kr[i] = *(const s16x8*)(src + (size_t)(b * S_LEN + j) * 512 + k0 + c * 8);
            }
        }
    };
    auto kwrite = [&](const s16x8* kr, int bufoff) {
        #pragma unroll
        for (int i = 0; i < 3; ++i) {
            int f = i * 1024 + tid;
            if (f < 2560) {
                int idx = (f < 1280) ? f : f - 1280;
                int r = idx >> 2, c = idx & 3;
                int off = bufoff + ((f < 1280) ? 0 : 10240) + swz32(r, c * 8);
                *(s16x8*)&smem[off] = kr[i];
            }
        }
    };
    auto qkstep = [&](int t, int bufoff) {
        const int k0 = t * 32;
        s16x8 zH = *(const s16x8*)(zh + qoff + k0 + fk);
        s16x8 zL = *(const s16x8*)(zl + qoff + k0 + fk);
        __builtin_amdgcn_s_setprio(1);
        #pragma unroll
        for (int tt = 0; tt < 5; ++tt) {
            if (tt < nt) {
                int krow = (tstart + tt) * 16 + frow;
                s16x8 bH = *(const s16x8*)&smem[bufoff + swz32(krow, fk)];
                s16x8 bL = *(const s16x8*)&smem[bufoff + 10240 + swz32(krow, fk)];
                acc[tt] = __builtin_amdgcn_mfma_f32_16x16x32_bf16(zH, bH, acc[tt], 0, 0, 0);
                acc[tt] = __builtin_amdgcn_mfma_f32_16x16x32_bf16(zH, bL, acc[tt], 0, 0, 0);
                acc[tt] = __builtin_amdgcn_mfma_f32_16x16x32_bf16(zL, bH, acc[tt], 0, 0, 0);
            }
        }
        __builtin_amdgcn_s_setprio(0);
    };

    // ---- QK^T: 16 steps, dbuf, reg-staged ----
    kload(0, krA);
    kwrite(krA, 0);
    kload(1, krB);
    __syncthreads();
    for (int tt2 = 0; tt2 < 16; tt2 += 2) {
        if (tt2 + 1 < 16) kwrite(krB, 20480);
        if (tt2 + 2 < 16) kload(tt2 + 2, krA);
        qkstep(tt2, 0);
        __syncthreads();
        if (tt2 + 1 < 16) {
            if (tt2 + 2 < 16) kwrite(krA, 0);
            if (tt2 + 3 < 16) kload(tt2 + 3, krB);
            qkstep(tt2 + 1, 20480);
            __syncthreads();
        }
    }

    // ---- softmax (stats alias buf1 region) ----
    float* sred_max = (float*)&smem[20480];          // [64][4]
    float* sred_sum = sred_max + 256;                // [64][4]
    #pragma unroll
    for (int e = 0; e < 4; ++e) {
        int r = g * 16 + rq + e;
        float m = NEG_INF_F;
        #pragma unroll
        for (int tt = 0; tt < 5; ++tt) {
            if (tt < nt) {
                int jj = (tstart + tt) * 16 + frow;
                int dj = jj - r, j = j0 + jj;
                if (dj >= 1 && dj <= 255 && j >= 0 && j < S_LEN) m = fmaxf(m, acc[tt][e]);
            }
        }
        #pragma unroll
        for (int d = 1; d < 16; d <<= 1) m = fmaxf(m, __shfl_xor(m, d));
        if (frow == 0) sred_max[r * 4 + q] = m;
    }
    __syncthreads();
    float sh[4];
    #pragma unroll
    for (int e = 0; e < 4; ++e) {
        int r = g * 16 + rq + e;
        float mx = fmaxf(fmaxf(sred_max[r * 4], sred_max[r * 4 + 1]),
                         fmaxf(sred_max[r * 4 + 2], sred_max[r * 4 + 3]));
        float s = 0.f;
        #pragma unroll
        for (int tt = 0; tt < 5; ++tt) {
            float pv = 0.f;
            if (tt < nt) {
                int jj = (tstart + tt) * 16 + frow;
                int dj = jj - r, j = j0 + jj;
                bool valid = (dj >= 1 && dj <= 255 && j >= 0 && j < S_LEN);
                pv = valid ? __expf(acc[tt][e] - mx) : 0.f;
            }
            acc[tt][e] = pv;
            s += pv;
        }
        #pragma unroll
        for (int d = 1; d < 16; d <<= 1) s += __shfl_xor(s, d);
        sh[e] = s;
    }
    if (frow == 0) {
        #pragma unroll
        for (int e = 0; e < 4; ++e) sred_sum[(g * 16 + rq + e) * 4 + q] = sh[e];
    }
    __syncthreads();
    float invv[4];
    #pragma unroll
    for (int e = 0; e < 4; ++e) {
        int r = g * 16 + rq + e;
        invv[e] = 1.f / (sred_sum[r * 4] + sred_sum[r * 4 + 1] +
                         sred_sum[r * 4 + 2] + sred_sum[r * 4 + 3]);
    }
    __syncthreads();                                 // stats consumed before VL writes
    // write normalized P into PL = smem[0..20480)
    #pragma unroll
    for (int tt = 0; tt < 5; ++tt) {
        if (tt < nt) {
            int t = tstart + tt;
            #pragma unroll
            for (int e = 0; e < 4; ++e) {
                int r = g * 16 + rq + e;
                smem[swz320(r, t * 16 + frow)] = f2bf(acc[tt][e] * invv[e]);
            }
        }
    }
    // band-complement zero-fill: tiles [0,g) by q0, tiles [g+17,20) by q3
    if (q == 0) {
        for (int t = 0; t < g; ++t)
            #pragma unroll
            for (int e = 0; e < 4; ++e)
                smem[swz320(g * 16 + rq + e, t * 16 + frow)] = 0;
    }
    if (q == 3) {
        for (int t = g + 17; t < 20; ++t)
            #pragma unroll
            for (int e = 0; e < 4; ++e)
                smem[swz320(g * 16 + rq + e, t * 16 + frow)] = 0;
    }

    // ---- PV: 8 d-steps of 64 d-rows, reg-staged V into VL ----
    s16x8 vreg[3];
    auto vload = [&](int ds) {
        const int d0 = ds * 64;
        #pragma unroll
        for (int i = 0; i < 3; ++i) {
            int f = i * 1024 + tid;                  // 2560 chunks (64 rows x 40)
            if (f < 2560) {
                int dr = f / 40, c8 = f - dr * 40;
                int jb = j0 + c8 * 8;
                jb = min(max(jb, 0), S_LEN - 8);     // clamped chunks have P==0
                vreg[i] = *(const s16x8*)&xT[(size_t)(b * 512 + d0 + dr) * S_LEN + jb];
            }
        }
    };
    auto vwrite = [&]() {
        #pragma unroll
        for (int i = 0; i < 3; ++i) {
            int f = i * 1024 + tid;
            if (f < 2560) {
                int dr = f / 40, c8 = f - dr * 40;
                *(s16x8*)&smem[20480 + swz320(dr, c8 * 8)] = vreg[i];
            }
        }
    };
    vload(0);
    for (int ds = 0; ds < 8; ++ds) {
        __syncthreads();                 // PL ready (ds=0) / prev VL reads done
        vwrite();
        __syncthreads();                 // VL visible
        if (ds < 7) vload(ds + 1);       // flies under this step's MFMA
        f32x4 po = {};
        __builtin_amdgcn_s_setprio(1);
        #pragma unroll
        for (int jt = 0; jt < 10; ++jt) {
            s16x8 a = *(const s16x8*)&smem[swz320(g * 16 + frow, jt * 32 + fk)];
            s16x8 bv = *(const s16x8*)&smem[20480 + swz320(q * 16 + frow, jt * 32 + fk)];
            po = __builtin_amdgcn_mfma_f32_16x16x32_bf16(a, bv, po, 0, 0, 0);
        }
        __builtin_amdgcn_s_setprio(0);
        #pragma unroll
        for (int e = 0; e < 4; ++e) {
            int r = mrow0 + g * 16 + rq + e;
            out[(size_t)r * 512 + ds * 64 + q * 16 + frow] = po[e];
        }
    }
}

extern "C" void kernel_launch(void* const* d_in, const int* in_sizes, int n_in,
                              void* d_out, int out_size, void* d_ws, size_t ws_size,
                              hipStream_t stream) {
    const float* x  = (const float*)d_in[0];
    const float* Wq = (const float*)d_in[1];
    const float* bq = (const float*)d_in[2];
    const float* Wk = (const float*)d_in[3];
    const float* bk = (const float*)d_in[4];
    (void)bk;
    float* out = (float*)d_out;

    u16* xh  = (u16*)d_ws;
    u16* xl  = xh + (size_t)8388608;
    u16* zh  = xl + (size_t)8388608;
    u16* zl  = zh + (size_t)8388608;
    u16* Mth = zl + (size_t)8388608;
    u16* Mtl = Mth + (size_t)262144;
    u16* xT  = Mtl + (size_t)262144;
    float* uv = (float*)(xT + (size_t)8388608);

    hipLaunchKernelGGL(split_xt_kernel, dim3(2048), dim3(256), 0, stream, x, xh, xl, xT);
    hipLaunchKernelGGL(mt_kernel, dim3(256), dim3(256), 0, stream, Wk, Wq, Mth, Mtl);
    hipLaunchKernelGGL(u_kernel, dim3(8), dim3(256), 0, stream, Wk, bq, uv);
    hipLaunchKernelGGL(z_kernel, dim3(512), dim3(512), 0, stream,
                       xh, xl, Mth, Mtl, uv, zh, zl);
    hipLaunchKernelGGL(attn_kernel, dim3(256), dim3(1024), 0, stream,
                       zh, zl, xh, xl, xT, out);
}

// Round 18
// 125.039 us; speedup vs baseline: 1.1344x; 1.1344x over previous
//
#include <hip/hip_runtime.h>
#include <hip/hip_bf16.h>

#define S_LEN 4096
#define NEG_INF_F (-1e30f)

typedef __attribute__((ext_vector_type(4))) float f32x4;
typedef __attribute__((ext_vector_type(8))) short s16x8;
typedef unsigned short u16;

static __device__ __forceinline__ u16 f2bf(float f) {
    unsigned u = __builtin_bit_cast(unsigned, f);
    unsigned r = u + 0x7FFFu + ((u >> 16) & 1u);
    return (u16)(r >> 16);
}
static __device__ __forceinline__ float bf2f(u16 h) {
    unsigned u = ((unsigned)h) << 16;
    return __builtin_bit_cast(float, u);
}
static __device__ __forceinline__ void split4(const float4 v, ushort4& hi, ushort4& lo) {
    hi.x = f2bf(v.x); lo.x = f2bf(v.x - bf2f(hi.x));
    hi.y = f2bf(v.y); lo.y = f2bf(v.y - bf2f(hi.y));
    hi.z = f2bf(v.z); lo.z = f2bf(v.z - bf2f(hi.z));
    hi.w = f2bf(v.w); lo.w = f2bf(v.w - bf2f(hi.w));
}
static __device__ __forceinline__ void gl_lds16(const void* g, void* l) {
    __builtin_amdgcn_global_load_lds(
        (const __attribute__((address_space(1))) void*)g,
        (__attribute__((address_space(3))) void*)l, 16, 0, 0);
}
// swizzled u16 offset within a [rows][64 u16] LDS tile
static __device__ __forceinline__ int swz64(int row, int col_u16) {
    return row * 64 + (col_u16 ^ ((row & 7) << 3));
}
// swizzled u16 offset within a [rows][32 u16] LDS tile
static __device__ __forceinline__ int swz32(int row, int col_u16) {
    return row * 32 + (col_u16 ^ (((row >> 1) & 3) << 3));
}
// swizzled u16 offset within a [rows][320 u16] LDS tile
static __device__ __forceinline__ int swz320(int row, int col_u16) {
    return row * 320 + (col_u16 ^ ((row & 7) << 3));
}
// XCD-chunked bijective swizzles
static __device__ __forceinline__ int xcd_swz512(int bid) {
    return (bid & 7) * 64 + (bid >> 3);
}
static __device__ __forceinline__ int xcd_swz256(int bid) {
    return (bid & 7) * 32 + (bid >> 3);
}

// ---------------- K0: merged prep = split_xt (2048) + mt 32x32 (256) + u (8) ----------------
__global__ __launch_bounds__(256) void prep_kernel(
    const float* __restrict__ x, const float* __restrict__ Wk,
    const float* __restrict__ Wq, const float* __restrict__ bq,
    u16* __restrict__ xh, u16* __restrict__ xl, u16* __restrict__ xT,
    u16* __restrict__ Mth, u16* __restrict__ Mtl, float* __restrict__ uvec) {
    __shared__ __align__(16) u16 sm[9216];           // 18432 B: max of the 3 roles
    const int bid = blockIdx.x;
    const int tid = threadIdx.x;

    if (bid < 2048) {
        // ---- split_xt role ----
        const int dt = bid & 7, st = (bid >> 3) & 63, b = bid >> 9;
        const int s0 = st * 64, d0 = dt * 64;
        u16 (*T)[72] = (u16(*)[72])sm;               // [64][72]
        #pragma unroll
        for (int i = 0; i < 4; ++i) {
            int idx = i * 256 + tid;
            int r = idx >> 4, c4 = (idx & 15) * 4;
            float4 v = *(const float4*)(x + (size_t)(b * S_LEN + s0 + r) * 512 + d0 + c4);
            ushort4 hi, lo; split4(v, hi, lo);
            *(ushort4*)(xh + (size_t)(b * S_LEN + s0 + r) * 512 + d0 + c4) = hi;
            *(ushort4*)(xl + (size_t)(b * S_LEN + s0 + r) * 512 + d0 + c4) = lo;
            *(ushort4*)&T[r][c4] = hi;
        }
        __syncthreads();
        #pragma unroll
        for (int i = 0; i < 2; ++i) {
            int idx = i * 256 + tid;
            int dr = idx >> 3, sc = idx & 7;
            s16x8 v;
            #pragma unroll
            for (int t = 0; t < 8; ++t) v[t] = (short)T[sc * 8 + t][dr];
            *(s16x8*)&xT[(size_t)(b * 512 + d0 + dr) * S_LEN + s0 + sc * 8] = v;
        }
    } else if (bid < 2304) {
        // ---- mt role: Mt = Wk^T @ Wq, 32x32 tiles ----
        const int mb = bid - 2048;
        const int bm = mb & 15, bn = mb >> 4;
        const int m0 = bm * 32, n0 = bn * 32;
        u16* Ath = sm;                               // [32*72]
        u16* Atl = sm + 2304;
        u16* Bth = sm + 4608;
        u16* Btl = sm + 6912;
        const int lane = tid & 63, w = tid >> 6;
        const int rg = w >> 1, cg = w & 1;
        const int frow = lane & 15, fk = (lane >> 4) * 8;
        f32x4 acc = {};

        for (int h0 = 0; h0 < 512; h0 += 64) {
            #pragma unroll
            for (int i = 0; i < 2; ++i) {
                int idx = i * 256 + tid;             // 512 slots: 64 h x 8 c4
                int h = idx >> 3, c4 = (idx & 7) * 4;
                float4 a = *(const float4*)(Wk + (size_t)(h0 + h) * 512 + m0 + c4);
                ushort4 ahi, alo; split4(a, ahi, alo);
                Ath[(c4 + 0) * 72 + h] = ahi.x; Atl[(c4 + 0) * 72 + h] = alo.x;
                Ath[(c4 + 1) * 72 + h] = ahi.y; Atl[(c4 + 1) * 72 + h] = alo.y;
                Ath[(c4 + 2) * 72 + h] = ahi.z; Atl[(c4 + 2) * 72 + h] = alo.z;
                Ath[(c4 + 3) * 72 + h] = ahi.w; Atl[(c4 + 3) * 72 + h] = alo.w;
                float4 b = *(const float4*)(Wq + (size_t)(h0 + h) * 512 + n0 + c4);
                ushort4 bhi, blo; split4(b, bhi, blo);
                Bth[(c4 + 0) * 72 + h] = bhi.x; Btl[(c4 + 0) * 72 + h] = blo.x;
                Bth[(c4 + 1) * 72 + h] = bhi.y; Btl[(c4 + 1) * 72 + h] = blo.y;
                Bth[(c4 + 2) * 72 + h] = bhi.z; Btl[(c4 + 2) * 72 + h] = blo.z;
                Bth[(c4 + 3) * 72 + h] = bhi.w; Btl[(c4 + 3) * 72 + h] = blo.w;
            }
            __syncthreads();
            #pragma unroll
            for (int kk = 0; kk < 2; ++kk) {
                s16x8 aH = *(const s16x8*)&Ath[(rg * 16 + frow) * 72 + kk * 32 + fk];
                s16x8 aL = *(const s16x8*)&Atl[(rg * 16 + frow) * 72 + kk * 32 + fk];
                s16x8 bH = *(const s16x8*)&Bth[(cg * 16 + frow) * 72 + kk * 32 + fk];
                s16x8 bL = *(const s16x8*)&Btl[(cg * 16 + frow) * 72 + kk * 32 + fk];
                acc = __builtin_amdgcn_mfma_f32_16x16x32_bf16(aH, bH, acc, 0, 0, 0);
                acc = __builtin_amdgcn_mfma_f32_16x16x32_bf16(aH, bL, acc, 0, 0, 0);
                acc = __builtin_amdgcn_mfma_f32_16x16x32_bf16(aL, bH, acc, 0, 0, 0);
            }
            __syncthreads();
        }
        int d1 = n0 + cg * 16 + frow;
        #pragma unroll
        for (int e = 0; e < 4; ++e) {
            int d2 = m0 + rg * 16 + (lane >> 4) * 4 + e;
            float v = acc[e];
            u16 hi = f2bf(v);
            Mth[(size_t)d2 * 512 + d1] = hi;
            Mtl[(size_t)d2 * 512 + d1] = f2bf(v - bf2f(hi));
        }
    } else {
        // ---- u role: u = Wk^T @ bq ----
        const int ub = bid - 2304;
        float* red = (float*)sm;                     // [4][64]
        const int c = tid & 63, hg = tid >> 6;
        const int d2 = ub * 64 + c;
        float acc = 0.f;
        for (int h = hg; h < 512; h += 4) acc += Wk[(size_t)h * 512 + d2] * bq[h];
        red[hg * 64 + c] = acc;
        __syncthreads();
        if (hg == 0)
            uvec[d2] = red[0 * 64 + c] + red[1 * 64 + c] + red[2 * 64 + c] + red[3 * 64 + c];
    }
}

// ---------------- K1: z = x @ Mt^T + u (gl_lds single-buffer, round-13) ----------------
__global__ __launch_bounds__(512) void z_kernel(
    const u16* __restrict__ xh, const u16* __restrict__ xl,
    const u16* __restrict__ Mth, const u16* __restrict__ Mtl,
    const float* __restrict__ u, u16* __restrict__ zh, u16* __restrict__ zl) {
    const int w_ = xcd_swz512((int)blockIdx.x);
    const int bm = w_ >> 2, bn = w_ & 3;
    const int m0 = bm * 128, n0 = bn * 128;
    __shared__ __align__(16) u16 Ah[128 * 64], Al[128 * 64];
    __shared__ __align__(16) u16 Bh[128 * 64], Bl[128 * 64];
    const int tid = threadIdx.x, lane = tid & 63, w = tid >> 6;
    const int rg = w >> 2, cg = w & 3;
    const int frow = lane & 15, fk = (lane >> 4) * 8;
    f32x4 acc[4][2] = {};

    for (int k0 = 0; k0 < 512; k0 += 64) {
        #pragma unroll
        for (int i = 0; i < 2; ++i) {
            int idx = i * 512 + tid;
            int r = idx >> 3, c = idx & 7;
            int sc = (c ^ (r & 7)) * 8;
            gl_lds16(xh + (size_t)(m0 + r) * 512 + k0 + sc, &Ah[idx * 8]);
            gl_lds16(xl + (size_t)(m0 + r) * 512 + k0 + sc, &Al[idx * 8]);
            gl_lds16(Mth + (size_t)(n0 + r) * 512 + k0 + sc, &Bh[idx * 8]);
            gl_lds16(Mtl + (size_t)(n0 + r) * 512 + k0 + sc, &Bl[idx * 8]);
        }
        __syncthreads();
        #pragma unroll
        for (int kk = 0; kk < 2; ++kk) {
            s16x8 aH[4], aL[4], bH[2], bL[2];
            #pragma unroll
            for (int mi = 0; mi < 4; ++mi) {
                int row = rg * 64 + mi * 16 + frow;
                aH[mi] = *(const s16x8*)&Ah[swz64(row, kk * 32 + fk)];
                aL[mi] = *(const s16x8*)&Al[swz64(row, kk * 32 + fk)];
            }
            #pragma unroll
            for (int ni = 0; ni < 2; ++ni) {
                int row = cg * 32 + ni * 16 + frow;
                bH[ni] = *(const s16x8*)&Bh[swz64(row, kk * 32 + fk)];
                bL[ni] = *(const s16x8*)&Bl[swz64(row, kk * 32 + fk)];
            }
            #pragma unroll
            for (int mi = 0; mi < 4; ++mi)
                #pragma unroll
                for (int ni = 0; ni < 2; ++ni) {
                    acc[mi][ni] = __builtin_amdgcn_mfma_f32_16x16x32_bf16(aH[mi], bH[ni], acc[mi][ni], 0, 0, 0);
                    acc[mi][ni] = __builtin_amdgcn_mfma_f32_16x16x32_bf16(aH[mi], bL[ni], acc[mi][ni], 0, 0, 0);
                    acc[mi][ni] = __builtin_amdgcn_mfma_f32_16x16x32_bf16(aL[mi], bH[ni], acc[mi][ni], 0, 0, 0);
                }
        }
        __syncthreads();
    }
    #pragma unroll
    for (int ni = 0; ni < 2; ++ni) {
        int col = n0 + cg * 32 + ni * 16 + frow;
        float uv = u[col];
        #pragma unroll
        for (int mi = 0; mi < 4; ++mi) {
            int rbase = m0 + rg * 64 + mi * 16 + (lane >> 4) * 4;
            #pragma unroll
            for (int e = 0; e < 4; ++e) {
                float v = acc[mi][ni][e] + uv;
                u16 hi = f2bf(v);
                zh[(size_t)(rbase + e) * 512 + col] = hi;
                zl[(size_t)(rbase + e) * 512 + col] = f2bf(v - bf2f(hi));
            }
        }
    }
}

// ---------------- K2: fused banded attention, 64-row tiles, reg-staged ----------------
// (round-13 version: 48.6us, VGPR 44, zero bank conflicts)
__global__ __launch_bounds__(1024, 4) void attn_kernel(
    const u16* __restrict__ zh, const u16* __restrict__ zl,
    const u16* __restrict__ xh, const u16* __restrict__ xl,
    const u16* __restrict__ xT, float* __restrict__ out) {
    const int w_ = xcd_swz256((int)blockIdx.x);
    const int b = w_ >> 6, it = w_ & 63;
    const int i0 = it * 64, j0 = i0 - 128;
    const int mrow0 = b * S_LEN + i0;

    __shared__ __align__(16) u16 smem[40960];        // 80 KB

    const int tid = threadIdx.x, lane = tid & 63, w = tid >> 6;
    const int g = w >> 2, q = w & 3;
    const int frow = lane & 15, fk = (lane >> 4) * 8;
    const int tstart = g + q * 4;
    const int nt = (q == 3) ? 5 : 4;
    const size_t qoff = (size_t)(mrow0 + g * 16 + frow) * 512;
    const int rq = (lane >> 4) * 4;

    f32x4 acc[5] = {};
    s16x8 krA[3], krB[3];

    auto kload = [&](int s, s16x8* kr) {
        const int k0 = s * 32;
        #pragma unroll
        for (int i = 0; i < 3; ++i) {
            int f = i * 1024 + tid;
            if (f < 2560) {
                int idx = (f < 1280) ? f : f - 1280;
                int r = idx >> 2, c = idx & 3;
                int j = min(max(j0 + r, 0), S_LEN - 1);
                const u16* src = (f < 1280) ? xh : xl;
                kr[i] = *(const s16x8*)(src + (size_t)(b * S_LEN + j) * 512 + k0 + c * 8);
            }
        }
    };
    auto kwrite = [&](const s16x8* kr, int bufoff) {
        #pragma unroll
        for (int i = 0; i < 3; ++i) {
            int f = i * 1024 + tid;
            if (f < 2560) {
                int idx = (f < 1280) ? f : f - 1280;
                int r = idx >> 2, c = idx & 3;
                int off = bufoff + ((f < 1280) ? 0 : 10240) + swz32(r, c * 8);
                *(s16x8*)&smem[off] = kr[i];
            }
        }
    };
    auto qkstep = [&](int t, int bufoff) {
        const int k0 = t * 32;
        s16x8 zH = *(const s16x8*)(zh + qoff + k0 + fk);
        s16x8 zL = *(const s16x8*)(zl + qoff + k0 + fk);
        __builtin_amdgcn_s_setprio(1);
        #pragma unroll
        for (int tt = 0; tt < 5; ++tt) {
            if (tt < nt) {
                int krow = (tstart + tt) * 16 + frow;
                s16x8 bH = *(const s16x8*)&smem[bufoff + swz32(krow, fk)];
                s16x8 bL = *(const s16x8*)&smem[bufoff + 10240 + swz32(krow, fk)];
                acc[tt] = __builtin_amdgcn_mfma_f32_16x16x32_bf16(zH, bH, acc[tt], 0, 0, 0);
                acc[tt] = __builtin_amdgcn_mfma_f32_16x16x32_bf16(zH, bL, acc[tt], 0, 0, 0);
                acc[tt] = __builtin_amdgcn_mfma_f32_16x16x32_bf16(zL, bH, acc[tt], 0, 0, 0);
            }
        }
        __builtin_amdgcn_s_setprio(0);
    };

    // ---- QK^T: 16 steps, dbuf, reg-staged ----
    kload(0, krA);
    kwrite(krA, 0);
    kload(1, krB);
    __syncthreads();
    for (int tt2 = 0; tt2 < 16; tt2 += 2) {
        if (tt2 + 1 < 16) kwrite(krB, 20480);
        if (tt2 + 2 < 16) kload(tt2 + 2, krA);
        qkstep(tt2, 0);
        __syncthreads();
        if (tt2 + 1 < 16) {
            if (tt2 + 2 < 16) kwrite(krA, 0);
            if (tt2 + 3 < 16) kload(tt2 + 3, krB);
            qkstep(tt2 + 1, 20480);
            __syncthreads();
        }
    }

    // ---- softmax (stats alias buf1 region) ----
    float* sred_max = (float*)&smem[20480];          // [64][4]
    float* sred_sum = sred_max + 256;                // [64][4]
    #pragma unroll
    for (int e = 0; e < 4; ++e) {
        int r = g * 16 + rq + e;
        float m = NEG_INF_F;
        #pragma unroll
        for (int tt = 0; tt < 5; ++tt) {
            if (tt < nt) {
                int jj = (tstart + tt) * 16 + frow;
                int dj = jj - r, j = j0 + jj;
                if (dj >= 1 && dj <= 255 && j >= 0 && j < S_LEN) m = fmaxf(m, acc[tt][e]);
            }
        }
        #pragma unroll
        for (int d = 1; d < 16; d <<= 1) m = fmaxf(m, __shfl_xor(m, d));
        if (frow == 0) sred_max[r * 4 + q] = m;
    }
    __syncthreads();
    float sh[4];
    #pragma unroll
    for (int e = 0; e < 4; ++e) {
        int r = g * 16 + rq + e;
        float mx = fmaxf(fmaxf(sred_max[r * 4], sred_max[r * 4 + 1]),
                         fmaxf(sred_max[r * 4 + 2], sred_max[r * 4 + 3]));
        float s = 0.f;
        #pragma unroll
        for (int tt = 0; tt < 5; ++tt) {
            float pv = 0.f;
            if (tt < nt) {
                int jj = (tstart + tt) * 16 + frow;
                int dj = jj - r, j = j0 + jj;
                bool valid = (dj >= 1 && dj <= 255 && j >= 0 && j < S_LEN);
                pv = valid ? __expf(acc[tt][e] - mx) : 0.f;
            }
            acc[tt][e] = pv;
            s += pv;
        }
        #pragma unroll
        for (int d = 1; d < 16; d <<= 1) s += __shfl_xor(s, d);
        sh[e] = s;
    }
    if (frow == 0) {
        #pragma unroll
        for (int e = 0; e < 4; ++e) sred_sum[(g * 16 + rq + e) * 4 + q] = sh[e];
    }
    __syncthreads();
    float invv[4];
    #pragma unroll
    for (int e = 0; e < 4; ++e) {
        int r = g * 16 + rq + e;
        invv[e] = 1.f / (sred_sum[r * 4] + sred_sum[r * 4 + 1] +
                         sred_sum[r * 4 + 2] + sred_sum[r * 4 + 3]);
    }
    __syncthreads();                                 // stats consumed before VL writes
    // write normalized P into PL = smem[0..20480)
    #pragma unroll
    for (int tt = 0; tt < 5; ++tt) {
        if (tt < nt) {
            int t = tstart + tt;
            #pragma unroll
            for (int e = 0; e < 4; ++e) {
                int r = g * 16 + rq + e;
                smem[swz320(r, t * 16 + frow)] = f2bf(acc[tt][e] * invv[e]);
            }
        }
    }
    // band-complement zero-fill: tiles [0,g) by q0, tiles [g+17,20) by q3
    if (q == 0) {
        for (int t = 0; t < g; ++t)
            #pragma unroll
            for (int e = 0; e < 4; ++e)
                smem[swz320(g * 16 + rq + e, t * 16 + frow)] = 0;
    }
    if (q == 3) {
        for (int t = g + 17; t < 20; ++t)
            #pragma unroll
            for (int e = 0; e < 4; ++e)
                smem[swz320(g * 16 + rq + e, t * 16 + frow)] = 0;
    }

    // ---- PV: 8 d-steps of 64 d-rows, reg-staged V into VL ----
    s16x8 vreg[3];
    auto vload = [&](int ds) {
        const int d0 = ds * 64;
        #pragma unroll
        for (int i = 0; i < 3; ++i) {
            int f = i * 1024 + tid;                  // 2560 chunks (64 rows x 40)
            if (f < 2560) {
                int dr = f / 40, c8 = f - dr * 40;
                int jb = j0 + c8 * 8;
                jb = min(max(jb, 0), S_LEN - 8);     // clamped chunks have P==0
                vreg[i] = *(const s16x8*)&xT[(size_t)(b * 512 + d0 + dr) * S_LEN + jb];
            }
        }
    };
    auto vwrite = [&]() {
        #pragma unroll
        for (int i = 0; i < 3; ++i) {
            int f = i * 1024 + tid;
            if (f < 2560) {
                int dr = f / 40, c8 = f - dr * 40;
                *(s16x8*)&smem[20480 + swz320(dr, c8 * 8)] = vreg[i];
            }
        }
    };
    vload(0);
    for (int ds = 0; ds < 8; ++ds) {
        __syncthreads();                 // PL ready (ds=0) / prev VL reads done
        vwrite();
        __syncthreads();                 // VL visible
        if (ds < 7) vload(ds + 1);       // flies under this step's MFMA
        f32x4 po = {};
        __builtin_amdgcn_s_setprio(1);
        #pragma unroll
        for (int jt = 0; jt < 10; ++jt) {
            s16x8 a = *(const s16x8*)&smem[swz320(g * 16 + frow, jt * 32 + fk)];
            s16x8 bv = *(const s16x8*)&smem[20480 + swz320(q * 16 + frow, jt * 32 + fk)];
            po = __builtin_amdgcn_mfma_f32_16x16x32_bf16(a, bv, po, 0, 0, 0);
        }
        __builtin_amdgcn_s_setprio(0);
        #pragma unroll
        for (int e = 0; e < 4; ++e) {
            int r = mrow0 + g * 16 + rq + e;
            out[(size_t)r * 512 + ds * 64 + q * 16 + frow] = po[e];
        }
    }
}

extern "C" void kernel_launch(void* const* d_in, const int* in_sizes, int n_in,
                              void* d_out, int out_size, void* d_ws, size_t ws_size,
                              hipStream_t stream) {
    const float* x  = (const float*)d_in[0];
    const float* Wq = (const float*)d_in[1];
    const float* bq = (const float*)d_in[2];
    const float* Wk = (const float*)d_in[3];
    const float* bk = (const float*)d_in[4];
    (void)bk;
    float* out = (float*)d_out;

    u16* xh  = (u16*)d_ws;
    u16* xl  = xh + (size_t)8388608;
    u16* zh  = xl + (size_t)8388608;
    u16* zl  = zh + (size_t)8388608;
    u16* Mth = zl + (size_t)8388608;
    u16* Mtl = Mth + (size_t)262144;
    u16* xT  = Mtl + (size_t)262144;
    float* uv = (float*)(xT + (size_t)8388608);

    hipLaunchKernelGGL(prep_kernel, dim3(2312), dim3(256), 0, stream,
                       x, Wk, Wq, bq, xh, xl, xT, Mth, Mtl, uv);
    hipLaunchKernelGGL(z_kernel, dim3(512), dim3(512), 0, stream,
                       xh, xl, Mth, Mtl, uv, zh, zl);
    hipLaunchKernelGGL(attn_kernel, dim3(256), dim3(1024), 0, stream,
                       zh, zl, xh, xl, xT, out);
}

// Round 19
// 122.896 us; speedup vs baseline: 1.1542x; 1.0174x over previous
//
#include <hip/hip_runtime.h>
#include <hip/hip_bf16.h>

#define S_LEN 4096
#define NEG_INF_F (-1e30f)

typedef __attribute__((ext_vector_type(4))) float f32x4;
typedef __attribute__((ext_vector_type(8))) short s16x8;
typedef unsigned short u16;

static __device__ __forceinline__ u16 f2bf(float f) {
    unsigned u = __builtin_bit_cast(unsigned, f);
    unsigned r = u + 0x7FFFu + ((u >> 16) & 1u);
    return (u16)(r >> 16);
}
static __device__ __forceinline__ float bf2f(u16 h) {
    unsigned u = ((unsigned)h) << 16;
    return __builtin_bit_cast(float, u);
}
static __device__ __forceinline__ void split4(const float4 v, ushort4& hi, ushort4& lo) {
    hi.x = f2bf(v.x); lo.x = f2bf(v.x - bf2f(hi.x));
    hi.y = f2bf(v.y); lo.y = f2bf(v.y - bf2f(hi.y));
    hi.z = f2bf(v.z); lo.z = f2bf(v.z - bf2f(hi.z));
    hi.w = f2bf(v.w); lo.w = f2bf(v.w - bf2f(hi.w));
}
static __device__ __forceinline__ void gl_lds16(const void* g, void* l) {
    __builtin_amdgcn_global_load_lds(
        (const __attribute__((address_space(1))) void*)g,
        (__attribute__((address_space(3))) void*)l, 16, 0, 0);
}
// swizzled u16 offset within a [rows][64 u16] LDS tile
static __device__ __forceinline__ int swz64(int row, int col_u16) {
    return row * 64 + (col_u16 ^ ((row & 7) << 3));
}
// swizzled u16 offset within a [rows][32 u16] LDS tile
static __device__ __forceinline__ int swz32(int row, int col_u16) {
    return row * 32 + (col_u16 ^ (((row >> 1) & 3) << 3));
}
// swizzled u16 offset within a [rows][320 u16] LDS tile
static __device__ __forceinline__ int swz320(int row, int col_u16) {
    return row * 320 + (col_u16 ^ ((row & 7) << 3));
}
// XCD-chunked bijective swizzles
static __device__ __forceinline__ int xcd_swz512(int bid) {
    return (bid & 7) * 64 + (bid >> 3);
}
static __device__ __forceinline__ int xcd_swz256(int bid) {
    return (bid & 7) * 32 + (bid >> 3);
}

// ---------------- K0: merged prep = mt (256) + u (8) + split_xt (2048) ----------------
// mt/u blocks FIRST so their serial-latency tail hides under split's HBM stream.
__global__ __launch_bounds__(256) void prep_kernel(
    const float* __restrict__ x, const float* __restrict__ Wk,
    const float* __restrict__ Wq, const float* __restrict__ bq,
    u16* __restrict__ xh, u16* __restrict__ xl, u16* __restrict__ xT,
    u16* __restrict__ Mth, u16* __restrict__ Mtl, float* __restrict__ uvec) {
    __shared__ __align__(16) u16 sm[9216];           // 18432 B: max of the 3 roles
    const int bid = blockIdx.x;
    const int tid = threadIdx.x;

    if (bid < 256) {
        // ---- mt role: Mt = Wk^T @ Wq, 32x32 tiles ----
        const int bm = bid & 15, bn = bid >> 4;
        const int m0 = bm * 32, n0 = bn * 32;
        u16* Ath = sm;                               // [32*72]
        u16* Atl = sm + 2304;
        u16* Bth = sm + 4608;
        u16* Btl = sm + 6912;
        const int lane = tid & 63, w = tid >> 6;
        const int rg = w >> 1, cg = w & 1;
        const int frow = lane & 15, fk = (lane >> 4) * 8;
        f32x4 acc = {};

        for (int h0 = 0; h0 < 512; h0 += 64) {
            #pragma unroll
            for (int i = 0; i < 2; ++i) {
                int idx = i * 256 + tid;             // 512 slots: 64 h x 8 c4
                int h = idx >> 3, c4 = (idx & 7) * 4;
                float4 a = *(const float4*)(Wk + (size_t)(h0 + h) * 512 + m0 + c4);
                ushort4 ahi, alo; split4(a, ahi, alo);
                Ath[(c4 + 0) * 72 + h] = ahi.x; Atl[(c4 + 0) * 72 + h] = alo.x;
                Ath[(c4 + 1) * 72 + h] = ahi.y; Atl[(c4 + 1) * 72 + h] = alo.y;
                Ath[(c4 + 2) * 72 + h] = ahi.z; Atl[(c4 + 2) * 72 + h] = alo.z;
                Ath[(c4 + 3) * 72 + h] = ahi.w; Atl[(c4 + 3) * 72 + h] = alo.w;
                float4 b = *(const float4*)(Wq + (size_t)(h0 + h) * 512 + n0 + c4);
                ushort4 bhi, blo; split4(b, bhi, blo);
                Bth[(c4 + 0) * 72 + h] = bhi.x; Btl[(c4 + 0) * 72 + h] = blo.x;
                Bth[(c4 + 1) * 72 + h] = bhi.y; Btl[(c4 + 1) * 72 + h] = blo.y;
                Bth[(c4 + 2) * 72 + h] = bhi.z; Btl[(c4 + 2) * 72 + h] = blo.z;
                Bth[(c4 + 3) * 72 + h] = bhi.w; Btl[(c4 + 3) * 72 + h] = blo.w;
            }
            __syncthreads();
            #pragma unroll
            for (int kk = 0; kk < 2; ++kk) {
                s16x8 aH = *(const s16x8*)&Ath[(rg * 16 + frow) * 72 + kk * 32 + fk];
                s16x8 aL = *(const s16x8*)&Atl[(rg * 16 + frow) * 72 + kk * 32 + fk];
                s16x8 bH = *(const s16x8*)&Bth[(cg * 16 + frow) * 72 + kk * 32 + fk];
                s16x8 bL = *(const s16x8*)&Btl[(cg * 16 + frow) * 72 + kk * 32 + fk];
                acc = __builtin_amdgcn_mfma_f32_16x16x32_bf16(aH, bH, acc, 0, 0, 0);
                acc = __builtin_amdgcn_mfma_f32_16x16x32_bf16(aH, bL, acc, 0, 0, 0);
                acc = __builtin_amdgcn_mfma_f32_16x16x32_bf16(aL, bH, acc, 0, 0, 0);
            }
            __syncthreads();
        }
        int d1 = n0 + cg * 16 + frow;
        #pragma unroll
        for (int e = 0; e < 4; ++e) {
            int d2 = m0 + rg * 16 + (lane >> 4) * 4 + e;
            float v = acc[e];
            u16 hi = f2bf(v);
            Mth[(size_t)d2 * 512 + d1] = hi;
            Mtl[(size_t)d2 * 512 + d1] = f2bf(v - bf2f(hi));
        }
    } else if (bid < 264) {
        // ---- u role: u = Wk^T @ bq ----
        const int ub = bid - 256;
        float* red = (float*)sm;                     // [4][64]
        const int c = tid & 63, hg = tid >> 6;
        const int d2 = ub * 64 + c;
        float acc = 0.f;
        for (int h = hg; h < 512; h += 4) acc += Wk[(size_t)h * 512 + d2] * bq[h];
        red[hg * 64 + c] = acc;
        __syncthreads();
        if (hg == 0)
            uvec[d2] = red[0 * 64 + c] + red[1 * 64 + c] + red[2 * 64 + c] + red[3 * 64 + c];
    } else {
        // ---- split_xt role ----
        const int sb = bid - 264;
        const int dt = sb & 7, st = (sb >> 3) & 63, b = sb >> 9;
        const int s0 = st * 64, d0 = dt * 64;
        u16 (*T)[74] = (u16(*)[74])sm;               // stride 74: conflict-free col reads
        #pragma unroll
        for (int i = 0; i < 4; ++i) {
            int idx = i * 256 + tid;
            int r = idx >> 4, c4 = (idx & 15) * 4;
            float4 v = *(const float4*)(x + (size_t)(b * S_LEN + s0 + r) * 512 + d0 + c4);
            ushort4 hi, lo; split4(v, hi, lo);
            *(ushort4*)(xh + (size_t)(b * S_LEN + s0 + r) * 512 + d0 + c4) = hi;
            *(ushort4*)(xl + (size_t)(b * S_LEN + s0 + r) * 512 + d0 + c4) = lo;
            T[r][c4 + 0] = hi.x;                     // scalar stores: 74-stride rows
            T[r][c4 + 1] = hi.y;                     // are not 8B-aligned for ushort4
            T[r][c4 + 2] = hi.z;
            T[r][c4 + 3] = hi.w;
        }
        __syncthreads();
        #pragma unroll
        for (int i = 0; i < 2; ++i) {
            int idx = i * 256 + tid;
            int dr = idx >> 3, sc = idx & 7;
            s16x8 v;
            #pragma unroll
            for (int t = 0; t < 8; ++t) v[t] = (short)T[sc * 8 + t][dr];
            *(s16x8*)&xT[(size_t)(b * 512 + d0 + dr) * S_LEN + s0 + sc * 8] = v;
        }
    }
}

// ---------------- K1: z = x @ Mt^T + u (gl_lds single-buffer, round-13) ----------------
__global__ __launch_bounds__(512) void z_kernel(
    const u16* __restrict__ xh, const u16* __restrict__ xl,
    const u16* __restrict__ Mth, const u16* __restrict__ Mtl,
    const float* __restrict__ u, u16* __restrict__ zh, u16* __restrict__ zl) {
    const int w_ = xcd_swz512((int)blockIdx.x);
    const int bm = w_ >> 2, bn = w_ & 3;
    const int m0 = bm * 128, n0 = bn * 128;
    __shared__ __align__(16) u16 Ah[128 * 64], Al[128 * 64];
    __shared__ __align__(16) u16 Bh[128 * 64], Bl[128 * 64];
    const int tid = threadIdx.x, lane = tid & 63, w = tid >> 6;
    const int rg = w >> 2, cg = w & 3;
    const int frow = lane & 15, fk = (lane >> 4) * 8;
    f32x4 acc[4][2] = {};

    for (int k0 = 0; k0 < 512; k0 += 64) {
        #pragma unroll
        for (int i = 0; i < 2; ++i) {
            int idx = i * 512 + tid;
            int r = idx >> 3, c = idx & 7;
            int sc = (c ^ (r & 7)) * 8;
            gl_lds16(xh + (size_t)(m0 + r) * 512 + k0 + sc, &Ah[idx * 8]);
            gl_lds16(xl + (size_t)(m0 + r) * 512 + k0 + sc, &Al[idx * 8]);
            gl_lds16(Mth + (size_t)(n0 + r) * 512 + k0 + sc, &Bh[idx * 8]);
            gl_lds16(Mtl + (size_t)(n0 + r) * 512 + k0 + sc, &Bl[idx * 8]);
        }
        __syncthreads();
        #pragma unroll
        for (int kk = 0; kk < 2; ++kk) {
            s16x8 aH[4], aL[4], bH[2], bL[2];
            #pragma unroll
            for (int mi = 0; mi < 4; ++mi) {
                int row = rg * 64 + mi * 16 + frow;
                aH[mi] = *(const s16x8*)&Ah[swz64(row, kk * 32 + fk)];
                aL[mi] = *(const s16x8*)&Al[swz64(row, kk * 32 + fk)];
            }
            #pragma unroll
            for (int ni = 0; ni < 2; ++ni) {
                int row = cg * 32 + ni * 16 + frow;
                bH[ni] = *(const s16x8*)&Bh[swz64(row, kk * 32 + fk)];
                bL[ni] = *(const s16x8*)&Bl[swz64(row, kk * 32 + fk)];
            }
            #pragma unroll
            for (int mi = 0; mi < 4; ++mi)
                #pragma unroll
                for (int ni = 0; ni < 2; ++ni) {
                    acc[mi][ni] = __builtin_amdgcn_mfma_f32_16x16x32_bf16(aH[mi], bH[ni], acc[mi][ni], 0, 0, 0);
                    acc[mi][ni] = __builtin_amdgcn_mfma_f32_16x16x32_bf16(aH[mi], bL[ni], acc[mi][ni], 0, 0, 0);
                    acc[mi][ni] = __builtin_amdgcn_mfma_f32_16x16x32_bf16(aL[mi], bH[ni], acc[mi][ni], 0, 0, 0);
                }
        }
        __syncthreads();
    }
    #pragma unroll
    for (int ni = 0; ni < 2; ++ni) {
        int col = n0 + cg * 32 + ni * 16 + frow;
        float uv = u[col];
        #pragma unroll
        for (int mi = 0; mi < 4; ++mi) {
            int rbase = m0 + rg * 64 + mi * 16 + (lane >> 4) * 4;
            #pragma unroll
            for (int e = 0; e < 4; ++e) {
                float v = acc[mi][ni][e] + uv;
                u16 hi = f2bf(v);
                zh[(size_t)(rbase + e) * 512 + col] = hi;
                zl[(size_t)(rbase + e) * 512 + col] = f2bf(v - bf2f(hi));
            }
        }
    }
}

// ---------------- K2: fused banded attention, 64-row tiles, reg-staged ----------------
// (round-13 version: 48.6us, VGPR 44, zero bank conflicts)
__global__ __launch_bounds__(1024, 4) void attn_kernel(
    const u16* __restrict__ zh, const u16* __restrict__ zl,
    const u16* __restrict__ xh, const u16* __restrict__ xl,
    const u16* __restrict__ xT, float* __restrict__ out) {
    const int w_ = xcd_swz256((int)blockIdx.x);
    const int b = w_ >> 6, it = w_ & 63;
    const int i0 = it * 64, j0 = i0 - 128;
    const int mrow0 = b * S_LEN + i0;

    __shared__ __align__(16) u16 smem[40960];        // 80 KB

    const int tid = threadIdx.x, lane = tid & 63, w = tid >> 6;
    const int g = w >> 2, q = w & 3;
    const int frow = lane & 15, fk = (lane >> 4) * 8;
    const int tstart = g + q * 4;
    const int nt = (q == 3) ? 5 : 4;
    const size_t qoff = (size_t)(mrow0 + g * 16 + frow) * 512;
    const int rq = (lane >> 4) * 4;

    f32x4 acc[5] = {};
    s16x8 krA[3], krB[3];

    auto kload = [&](int s, s16x8* kr) {
        const int k0 = s * 32;
        #pragma unroll
        for (int i = 0; i < 3; ++i) {
            int f = i * 1024 + tid;
            if (f < 2560) {
                int idx = (f < 1280) ? f : f - 1280;
                int r = idx >> 2, c = idx & 3;
                int j = min(max(j0 + r, 0), S_LEN - 1);
                const u16* src = (f < 1280) ? xh : xl;
                kr[i] = *(const s16x8*)(src + (size_t)(b * S_LEN + j) * 512 + k0 + c * 8);
            }
        }
    };
    auto kwrite = [&](const s16x8* kr, int bufoff) {
        #pragma unroll
        for (int i = 0; i < 3; ++i) {
            int f = i * 1024 + tid;
            if (f < 2560) {
                int idx = (f < 1280) ? f : f - 1280;
                int r = idx >> 2, c = idx & 3;
                int off = bufoff + ((f < 1280) ? 0 : 10240) + swz32(r, c * 8);
                *(s16x8*)&smem[off] = kr[i];
            }
        }
    };
    auto qkstep = [&](int t, int bufoff) {
        const int k0 = t * 32;
        s16x8 zH = *(const s16x8*)(zh + qoff + k0 + fk);
        s16x8 zL = *(const s16x8*)(zl + qoff + k0 + fk);
        __builtin_amdgcn_s_setprio(1);
        #pragma unroll
        for (int tt = 0; tt < 5; ++tt) {
            if (tt < nt) {
                int krow = (tstart + tt) * 16 + frow;
                s16x8 bH = *(const s16x8*)&smem[bufoff + swz32(krow, fk)];
                s16x8 bL = *(const s16x8*)&smem[bufoff + 10240 + swz32(krow, fk)];
                acc[tt] = __builtin_amdgcn_mfma_f32_16x16x32_bf16(zH, bH, acc[tt], 0, 0, 0);
                acc[tt] = __builtin_amdgcn_mfma_f32_16x16x32_bf16(zH, bL, acc[tt], 0, 0, 0);
                acc[tt] = __builtin_amdgcn_mfma_f32_16x16x32_bf16(zL, bH, acc[tt], 0, 0, 0);
            }
        }
        __builtin_amdgcn_s_setprio(0);
    };

    // ---- QK^T: 16 steps, dbuf, reg-staged ----
    kload(0, krA);
    kwrite(krA, 0);
    kload(1, krB);
    __syncthreads();
    for (int tt2 = 0; tt2 < 16; tt2 += 2) {
        if (tt2 + 1 < 16) kwrite(krB, 20480);
        if (tt2 + 2 < 16) kload(tt2 + 2, krA);
        qkstep(tt2, 0);
        __syncthreads();
        if (tt2 + 1 < 16) {
            if (tt2 + 2 < 16) kwrite(krA, 0);
            if (tt2 + 3 < 16) kload(tt2 + 3, krB);
            qkstep(tt2 + 1, 20480);
            __syncthreads();
        }
    }

    // ---- softmax (stats alias buf1 region) ----
    float* sred_max = (float*)&smem[20480];          // [64][4]
    float* sred_sum = sred_max + 256;                // [64][4]
    #pragma unroll
    for (int e = 0; e < 4; ++e) {
        int r = g * 16 + rq + e;
        float m = NEG_INF_F;
        #pragma unroll
        for (int tt = 0; tt < 5; ++tt) {
            if (tt < nt) {
                int jj = (tstart + tt) * 16 + frow;
                int dj = jj - r, j = j0 + jj;
                if (dj >= 1 && dj <= 255 && j >= 0 && j < S_LEN) m = fmaxf(m, acc[tt][e]);
            }
        }
        #pragma unroll
        for (int d = 1; d < 16; d <<= 1) m = fmaxf(m, __shfl_xor(m, d));
        if (frow == 0) sred_max[r * 4 + q] = m;
    }
    __syncthreads();
    float sh[4];
    #pragma unroll
    for (int e = 0; e < 4; ++e) {
        int r = g * 16 + rq + e;
        float mx = fmaxf(fmaxf(sred_max[r * 4], sred_max[r * 4 + 1]),
                         fmaxf(sred_max[r * 4 + 2], sred_max[r * 4 + 3]));
        float s = 0.f;
        #pragma unroll
        for (int tt = 0; tt < 5; ++tt) {
            float pv = 0.f;
            if (tt < nt) {
                int jj = (tstart + tt) * 16 + frow;
                int dj = jj - r, j = j0 + jj;
                bool valid = (dj >= 1 && dj <= 255 && j >= 0 && j < S_LEN);
                pv = valid ? __expf(acc[tt][e] - mx) : 0.f;
            }
            acc[tt][e] = pv;
            s += pv;
        }
        #pragma unroll
        for (int d = 1; d < 16; d <<= 1) s += __shfl_xor(s, d);
        sh[e] = s;
    }
    if (frow == 0) {
        #pragma unroll
        for (int e = 0; e < 4; ++e) sred_sum[(g * 16 + rq + e) * 4 + q] = sh[e];
    }
    __syncthreads();
    float invv[4];
    #pragma unroll
    for (int e = 0; e < 4; ++e) {
        int r = g * 16 + rq + e;
        invv[e] = 1.f / (sred_sum[r * 4] + sred_sum[r * 4 + 1] +
                         sred_sum[r * 4 + 2] + sred_sum[r * 4 + 3]);
    }
    __syncthreads();                                 // stats consumed before VL writes
    // write normalized P into PL = smem[0..20480)
    #pragma unroll
    for (int tt = 0; tt < 5; ++tt) {
        if (tt < nt) {
            int t = tstart + tt;
            #pragma unroll
            for (int e = 0; e < 4; ++e) {
                int r = g * 16 + rq + e;
                smem[swz320(r, t * 16 + frow)] = f2bf(acc[tt][e] * invv[e]);
            }
        }
    }
    // band-complement zero-fill: tiles [0,g) by q0, tiles [g+17,20) by q3
    if (q == 0) {
        for (int t = 0; t < g; ++t)
            #pragma unroll
            for (int e = 0; e < 4; ++e)
                smem[swz320(g * 16 + rq + e, t * 16 + frow)] = 0;
    }
    if (q == 3) {
        for (int t = g + 17; t < 20; ++t)
            #pragma unroll
            for (int e = 0; e < 4; ++e)
                smem[swz320(g * 16 + rq + e, t * 16 + frow)] = 0;
    }

    // ---- PV: 8 d-steps of 64 d-rows, reg-staged V into VL ----
    s16x8 vreg[3];
    auto vload = [&](int ds) {
        const int d0 = ds * 64;
        #pragma unroll
        for (int i = 0; i < 3; ++i) {
            int f = i * 1024 + tid;                  // 2560 chunks (64 rows x 40)
            if (f < 2560) {
                int dr = f / 40, c8 = f - dr * 40;
                int jb = j0 + c8 * 8;
                jb = min(max(jb, 0), S_LEN - 8);     // clamped chunks have P==0
                vreg[i] = *(const s16x8*)&xT[(size_t)(b * 512 + d0 + dr) * S_LEN + jb];
            }
        }
    };
    auto vwrite = [&]() {
        #pragma unroll
        for (int i = 0; i < 3; ++i) {
            int f = i * 1024 + tid;
            if (f < 2560) {
                int dr = f / 40, c8 = f - dr * 40;
                *(s16x8*)&smem[20480 + swz320(dr, c8 * 8)] = vreg[i];
            }
        }
    };
    vload(0);
    for (int ds = 0; ds < 8; ++ds) {
        __syncthreads();                 // PL ready (ds=0) / prev VL reads done
        vwrite();
        __syncthreads();                 // VL visible
        if (ds < 7) vload(ds + 1);       // flies under this step's MFMA
        f32x4 po = {};
        __builtin_amdgcn_s_setprio(1);
        #pragma unroll
        for (int jt = 0; jt < 10; ++jt) {
            s16x8 a = *(const s16x8*)&smem[swz320(g * 16 + frow, jt * 32 + fk)];
            s16x8 bv = *(const s16x8*)&smem[20480 + swz320(q * 16 + frow, jt * 32 + fk)];
            po = __builtin_amdgcn_mfma_f32_16x16x32_bf16(a, bv, po, 0, 0, 0);
        }
        __builtin_amdgcn_s_setprio(0);
        #pragma unroll
        for (int e = 0; e < 4; ++e) {
            int r = mrow0 + g * 16 + rq + e;
            out[(size_t)r * 512 + ds * 64 + q * 16 + frow] = po[e];
        }
    }
}

extern "C" void kernel_launch(void* const* d_in, const int* in_sizes, int n_in,
                              void* d_out, int out_size, void* d_ws, size_t ws_size,
                              hipStream_t stream) {
    const float* x  = (const float*)d_in[0];
    const float* Wq = (const float*)d_in[1];
    const float* bq = (const float*)d_in[2];
    const float* Wk = (const float*)d_in[3];
    const float* bk = (const float*)d_in[4];
    (void)bk;
    float* out = (float*)d_out;

    u16* xh  = (u16*)d_ws;
    u16* xl  = xh + (size_t)8388608;
    u16* zh  = xl + (size_t)8388608;
    u16* zl  = zh + (size_t)8388608;
    u16* Mth = zl + (size_t)8388608;
    u16* Mtl = Mth + (size_t)262144;
    u16* xT  = Mtl + (size_t)262144;
    float* uv = (float*)(xT + (size_t)8388608);

    hipLaunchKernelGGL(prep_kernel, dim3(2312), dim3(256), 0, stream,
                       x, Wk, Wq, bq, xh, xl, xT, Mth, Mtl, uv);
    hipLaunchKernelGGL(z_kernel, dim3(512), dim3(512), 0, stream,
                       xh, xl, Mth, Mtl, uv, zh, zl);
    hipLaunchKernelGGL(attn_kernel, dim3(256), dim3(1024), 0, stream,
                       zh, zl, xh, xl, xT, out);
}

// Round 20
// 118.787 us; speedup vs baseline: 1.1941x; 1.0346x over previous
//
#include <hip/hip_runtime.h>
#include <hip/hip_bf16.h>

#define S_LEN 4096
#define NEG_INF_F (-1e30f)

typedef __attribute__((ext_vector_type(4))) float f32x4;
typedef __attribute__((ext_vector_type(8))) short s16x8;
typedef unsigned short u16;

static __device__ __forceinline__ u16 f2bf(float f) {
    unsigned u = __builtin_bit_cast(unsigned, f);
    unsigned r = u + 0x7FFFu + ((u >> 16) & 1u);
    return (u16)(r >> 16);
}
static __device__ __forceinline__ float bf2f(u16 h) {
    unsigned u = ((unsigned)h) << 16;
    return __builtin_bit_cast(float, u);
}
static __device__ __forceinline__ void split4(const float4 v, ushort4& hi, ushort4& lo) {
    hi.x = f2bf(v.x); lo.x = f2bf(v.x - bf2f(hi.x));
    hi.y = f2bf(v.y); lo.y = f2bf(v.y - bf2f(hi.y));
    hi.z = f2bf(v.z); lo.z = f2bf(v.z - bf2f(hi.z));
    hi.w = f2bf(v.w); lo.w = f2bf(v.w - bf2f(hi.w));
}
static __device__ __forceinline__ void gl_lds16(const void* g, void* l) {
    __builtin_amdgcn_global_load_lds(
        (const __attribute__((address_space(1))) void*)g,
        (__attribute__((address_space(3))) void*)l, 16, 0, 0);
}
// swizzled u16 offset within a [rows][64 u16] LDS tile
static __device__ __forceinline__ int swz64(int row, int col_u16) {
    return row * 64 + (col_u16 ^ ((row & 7) << 3));
}
// swizzled u16 offset within a [rows][32 u16] LDS tile
static __device__ __forceinline__ int swz32(int row, int col_u16) {
    return row * 32 + (col_u16 ^ (((row >> 1) & 3) << 3));
}
// swizzled u16 offset within a [rows][320 u16] LDS tile
static __device__ __forceinline__ int swz320(int row, int col_u16) {
    return row * 320 + (col_u16 ^ ((row & 7) << 3));
}
// XCD-chunked bijective swizzles
static __device__ __forceinline__ int xcd_swz512(int bid) {
    return (bid & 7) * 64 + (bid >> 3);
}
static __device__ __forceinline__ int xcd_swz256(int bid) {
    return (bid & 7) * 32 + (bid >> 3);
}

// ---------------- K0: merged prep = mt (256) + u (8) + split_xt (2048) ----------------
// mt/u blocks FIRST so their serial-latency tail hides under split's HBM stream.
__global__ __launch_bounds__(256) void prep_kernel(
    const float* __restrict__ x, const float* __restrict__ Wk,
    const float* __restrict__ Wq, const float* __restrict__ bq,
    u16* __restrict__ xh, u16* __restrict__ xl, u16* __restrict__ xT,
    u16* __restrict__ Mth, u16* __restrict__ Mtl, float* __restrict__ uvec) {
    __shared__ __align__(16) u16 sm[9216];           // 18432 B: max of the 3 roles
    const int bid = blockIdx.x;
    const int tid = threadIdx.x;

    if (bid < 256) {
        // ---- mt role: Mt = Wk^T @ Wq, 32x32 tiles ----
        const int bm = bid & 15, bn = bid >> 4;
        const int m0 = bm * 32, n0 = bn * 32;
        u16* Ath = sm;                               // [32*72]
        u16* Atl = sm + 2304;
        u16* Bth = sm + 4608;
        u16* Btl = sm + 6912;
        const int lane = tid & 63, w = tid >> 6;
        const int rg = w >> 1, cg = w & 1;
        const int frow = lane & 15, fk = (lane >> 4) * 8;
        f32x4 acc = {};

        for (int h0 = 0; h0 < 512; h0 += 64) {
            #pragma unroll
            for (int i = 0; i < 2; ++i) {
                int idx = i * 256 + tid;             // 512 slots: 64 h x 8 c4
                int h = idx >> 3, c4 = (idx & 7) * 4;
                float4 a = *(const float4*)(Wk + (size_t)(h0 + h) * 512 + m0 + c4);
                ushort4 ahi, alo; split4(a, ahi, alo);
                Ath[(c4 + 0) * 72 + h] = ahi.x; Atl[(c4 + 0) * 72 + h] = alo.x;
                Ath[(c4 + 1) * 72 + h] = ahi.y; Atl[(c4 + 1) * 72 + h] = alo.y;
                Ath[(c4 + 2) * 72 + h] = ahi.z; Atl[(c4 + 2) * 72 + h] = alo.z;
                Ath[(c4 + 3) * 72 + h] = ahi.w; Atl[(c4 + 3) * 72 + h] = alo.w;
                float4 b = *(const float4*)(Wq + (size_t)(h0 + h) * 512 + n0 + c4);
                ushort4 bhi, blo; split4(b, bhi, blo);
                Bth[(c4 + 0) * 72 + h] = bhi.x; Btl[(c4 + 0) * 72 + h] = blo.x;
                Bth[(c4 + 1) * 72 + h] = bhi.y; Btl[(c4 + 1) * 72 + h] = blo.y;
                Bth[(c4 + 2) * 72 + h] = bhi.z; Btl[(c4 + 2) * 72 + h] = blo.z;
                Bth[(c4 + 3) * 72 + h] = bhi.w; Btl[(c4 + 3) * 72 + h] = blo.w;
            }
            __syncthreads();
            #pragma unroll
            for (int kk = 0; kk < 2; ++kk) {
                s16x8 aH = *(const s16x8*)&Ath[(rg * 16 + frow) * 72 + kk * 32 + fk];
                s16x8 aL = *(const s16x8*)&Atl[(rg * 16 + frow) * 72 + kk * 32 + fk];
                s16x8 bH = *(const s16x8*)&Bth[(cg * 16 + frow) * 72 + kk * 32 + fk];
                s16x8 bL = *(const s16x8*)&Btl[(cg * 16 + frow) * 72 + kk * 32 + fk];
                acc = __builtin_amdgcn_mfma_f32_16x16x32_bf16(aH, bH, acc, 0, 0, 0);
                acc = __builtin_amdgcn_mfma_f32_16x16x32_bf16(aH, bL, acc, 0, 0, 0);
                acc = __builtin_amdgcn_mfma_f32_16x16x32_bf16(aL, bH, acc, 0, 0, 0);
            }
            __syncthreads();
        }
        int d1 = n0 + cg * 16 + frow;
        #pragma unroll
        for (int e = 0; e < 4; ++e) {
            int d2 = m0 + rg * 16 + (lane >> 4) * 4 + e;
            float v = acc[e];
            u16 hi = f2bf(v);
            Mth[(size_t)d2 * 512 + d1] = hi;
            Mtl[(size_t)d2 * 512 + d1] = f2bf(v - bf2f(hi));
        }
    } else if (bid < 264) {
        // ---- u role: u = Wk^T @ bq ----
        const int ub = bid - 256;
        float* red = (float*)sm;                     // [4][64]
        const int c = tid & 63, hg = tid >> 6;
        const int d2 = ub * 64 + c;
        float acc = 0.f;
        for (int h = hg; h < 512; h += 4) acc += Wk[(size_t)h * 512 + d2] * bq[h];
        red[hg * 64 + c] = acc;
        __syncthreads();
        if (hg == 0)
            uvec[d2] = red[0 * 64 + c] + red[1 * 64 + c] + red[2 * 64 + c] + red[3 * 64 + c];
    } else {
        // ---- split_xt role ----
        const int sb = bid - 264;
        const int dt = sb & 7, st = (sb >> 3) & 63, b = sb >> 9;
        const int s0 = st * 64, d0 = dt * 64;
        u16 (*T)[74] = (u16(*)[74])sm;               // stride 74 (37 dw, 37%32=5)
        #pragma unroll
        for (int i = 0; i < 4; ++i) {
            int idx = i * 256 + tid;
            int r = idx >> 4, c4 = (idx & 15) * 4;
            float4 v = *(const float4*)(x + (size_t)(b * S_LEN + s0 + r) * 512 + d0 + c4);
            ushort4 hi, lo; split4(v, hi, lo);
            *(ushort4*)(xh + (size_t)(b * S_LEN + s0 + r) * 512 + d0 + c4) = hi;
            *(ushort4*)(xl + (size_t)(b * S_LEN + s0 + r) * 512 + d0 + c4) = lo;
            T[r][c4 + 0] = hi.x;                     // scalar stores (2-way, free)
            T[r][c4 + 1] = hi.y;
            T[r][c4 + 2] = hi.z;
            T[r][c4 + 3] = hi.w;
        }
        __syncthreads();
        {
            // u32 transpose reads: each thread builds TWO d-rows from 8 u32 reads
            // banks = 8*sc + 5*t + drp (mod 32) -> 2-way, conflict-free
            const int drp = tid >> 3, sc = tid & 7;  // 32 row-pairs x 8 s-chunks
            s16x8 v0, v1;
            #pragma unroll
            for (int t = 0; t < 8; ++t) {
                unsigned wv = *(const unsigned*)&T[sc * 8 + t][drp * 2];
                v0[t] = (short)(wv & 0xFFFFu);
                v1[t] = (short)(wv >> 16);
            }
            size_t base = (size_t)(b * 512 + d0 + drp * 2) * S_LEN + s0 + sc * 8;
            *(s16x8*)&xT[base] = v0;
            *(s16x8*)&xT[base + S_LEN] = v1;
        }
    }
}

// ---------------- K1: z = x @ Mt^T + u (gl_lds single-buffer, round-13) ----------------
__global__ __launch_bounds__(512) void z_kernel(
    const u16* __restrict__ xh, const u16* __restrict__ xl,
    const u16* __restrict__ Mth, const u16* __restrict__ Mtl,
    const float* __restrict__ u, u16* __restrict__ zh, u16* __restrict__ zl) {
    const int w_ = xcd_swz512((int)blockIdx.x);
    const int bm = w_ >> 2, bn = w_ & 3;
    const int m0 = bm * 128, n0 = bn * 128;
    __shared__ __align__(16) u16 Ah[128 * 64], Al[128 * 64];
    __shared__ __align__(16) u16 Bh[128 * 64], Bl[128 * 64];
    const int tid = threadIdx.x, lane = tid & 63, w = tid >> 6;
    const int rg = w >> 2, cg = w & 3;
    const int frow = lane & 15, fk = (lane >> 4) * 8;
    f32x4 acc[4][2] = {};

    for (int k0 = 0; k0 < 512; k0 += 64) {
        #pragma unroll
        for (int i = 0; i < 2; ++i) {
            int idx = i * 512 + tid;
            int r = idx >> 3, c = idx & 7;
            int sc = (c ^ (r & 7)) * 8;
            gl_lds16(xh + (size_t)(m0 + r) * 512 + k0 + sc, &Ah[idx * 8]);
            gl_lds16(xl + (size_t)(m0 + r) * 512 + k0 + sc, &Al[idx * 8]);
            gl_lds16(Mth + (size_t)(n0 + r) * 512 + k0 + sc, &Bh[idx * 8]);
            gl_lds16(Mtl + (size_t)(n0 + r) * 512 + k0 + sc, &Bl[idx * 8]);
        }
        __syncthreads();
        #pragma unroll
        for (int kk = 0; kk < 2; ++kk) {
            s16x8 aH[4], aL[4], bH[2], bL[2];
            #pragma unroll
            for (int mi = 0; mi < 4; ++mi) {
                int row = rg * 64 + mi * 16 + frow;
                aH[mi] = *(const s16x8*)&Ah[swz64(row, kk * 32 + fk)];
                aL[mi] = *(const s16x8*)&Al[swz64(row, kk * 32 + fk)];
            }
            #pragma unroll
            for (int ni = 0; ni < 2; ++ni) {
                int row = cg * 32 + ni * 16 + frow;
                bH[ni] = *(const s16x8*)&Bh[swz64(row, kk * 32 + fk)];
                bL[ni] = *(const s16x8*)&Bl[swz64(row, kk * 32 + fk)];
            }
            #pragma unroll
            for (int mi = 0; mi < 4; ++mi)
                #pragma unroll
                for (int ni = 0; ni < 2; ++ni) {
                    acc[mi][ni] = __builtin_amdgcn_mfma_f32_16x16x32_bf16(aH[mi], bH[ni], acc[mi][ni], 0, 0, 0);
                    acc[mi][ni] = __builtin_amdgcn_mfma_f32_16x16x32_bf16(aH[mi], bL[ni], acc[mi][ni], 0, 0, 0);
                    acc[mi][ni] = __builtin_amdgcn_mfma_f32_16x16x32_bf16(aL[mi], bH[ni], acc[mi][ni], 0, 0, 0);
                }
        }
        __syncthreads();
    }
    #pragma unroll
    for (int ni = 0; ni < 2; ++ni) {
        int col = n0 + cg * 32 + ni * 16 + frow;
        float uv = u[col];
        #pragma unroll
        for (int mi = 0; mi < 4; ++mi) {
            int rbase = m0 + rg * 64 + mi * 16 + (lane >> 4) * 4;
            #pragma unroll
            for (int e = 0; e < 4; ++e) {
                float v = acc[mi][ni][e] + uv;
                u16 hi = f2bf(v);
                zh[(size_t)(rbase + e) * 512 + col] = hi;
                zl[(size_t)(rbase + e) * 512 + col] = f2bf(v - bf2f(hi));
            }
        }
    }
}

// ---------------- K2: fused banded attention, 64-row tiles, reg-staged ----------------
// (round-13 version: 48.6us, VGPR 44, zero bank conflicts)
__global__ __launch_bounds__(1024, 4) void attn_kernel(
    const u16* __restrict__ zh, const u16* __restrict__ zl,
    const u16* __restrict__ xh, const u16* __restrict__ xl,
    const u16* __restrict__ xT, float* __restrict__ out) {
    const int w_ = xcd_swz256((int)blockIdx.x);
    const int b = w_ >> 6, it = w_ & 63;
    const int i0 = it * 64, j0 = i0 - 128;
    const int mrow0 = b * S_LEN + i0;

    __shared__ __align__(16) u16 smem[40960];        // 80 KB

    const int tid = threadIdx.x, lane = tid & 63, w = tid >> 6;
    const int g = w >> 2, q = w & 3;
    const int frow = lane & 15, fk = (lane >> 4) * 8;
    const int tstart = g + q * 4;
    const int nt = (q == 3) ? 5 : 4;
    const size_t qoff = (size_t)(mrow0 + g * 16 + frow) * 512;
    const int rq = (lane >> 4) * 4;

    f32x4 acc[5] = {};
    s16x8 krA[3], krB[3];

    auto kload = [&](int s, s16x8* kr) {
        const int k0 = s * 32;
        #pragma unroll
        for (int i = 0; i < 3; ++i) {
            int f = i * 1024 + tid;
            if (f < 2560) {
                int idx = (f < 1280) ? f : f - 1280;
                int r = idx >> 2, c = idx & 3;
                int j = min(max(j0 + r, 0), S_LEN - 1);
                const u16* src = (f < 1280) ? xh : xl;
                kr[i] = *(const s16x8*)(src + (size_t)(b * S_LEN + j) * 512 + k0 + c * 8);
            }
        }
    };
    auto kwrite = [&](const s16x8* kr, int bufoff) {
        #pragma unroll
        for (int i = 0; i < 3; ++i) {
            int f = i * 1024 + tid;
            if (f < 2560) {
                int idx = (f < 1280) ? f : f - 1280;
                int r = idx >> 2, c = idx & 3;
                int off = bufoff + ((f < 1280) ? 0 : 10240) + swz32(r, c * 8);
                *(s16x8*)&smem[off] = kr[i];
            }
        }
    };
    auto qkstep = [&](int t, int bufoff) {
        const int k0 = t * 32;
        s16x8 zH = *(const s16x8*)(zh + qoff + k0 + fk);
        s16x8 zL = *(const s16x8*)(zl + qoff + k0 + fk);
        __builtin_amdgcn_s_setprio(1);
        #pragma unroll
        for (int tt = 0; tt < 5; ++tt) {
            if (tt < nt) {
                int krow = (tstart + tt) * 16 + frow;
                s16x8 bH = *(const s16x8*)&smem[bufoff + swz32(krow, fk)];
                s16x8 bL = *(const s16x8*)&smem[bufoff + 10240 + swz32(krow, fk)];
                acc[tt] = __builtin_amdgcn_mfma_f32_16x16x32_bf16(zH, bH, acc[tt], 0, 0, 0);
                acc[tt] = __builtin_amdgcn_mfma_f32_16x16x32_bf16(zH, bL, acc[tt], 0, 0, 0);
                acc[tt] = __builtin_amdgcn_mfma_f32_16x16x32_bf16(zL, bH, acc[tt], 0, 0, 0);
            }
        }
        __builtin_amdgcn_s_setprio(0);
    };

    // ---- QK^T: 16 steps, dbuf, reg-staged ----
    kload(0, krA);
    kwrite(krA, 0);
    kload(1, krB);
    __syncthreads();
    for (int tt2 = 0; tt2 < 16; tt2 += 2) {
        if (tt2 + 1 < 16) kwrite(krB, 20480);
        if (tt2 + 2 < 16) kload(tt2 + 2, krA);
        qkstep(tt2, 0);
        __syncthreads();
        if (tt2 + 1 < 16) {
            if (tt2 + 2 < 16) kwrite(krA, 0);
            if (tt2 + 3 < 16) kload(tt2 + 3, krB);
            qkstep(tt2 + 1, 20480);
            __syncthreads();
        }
    }

    // ---- softmax (stats alias buf1 region) ----
    float* sred_max = (float*)&smem[20480];          // [64][4]
    float* sred_sum = sred_max + 256;                // [64][4]
    #pragma unroll
    for (int e = 0; e < 4; ++e) {
        int r = g * 16 + rq + e;
        float m = NEG_INF_F;
        #pragma unroll
        for (int tt = 0; tt < 5; ++tt) {
            if (tt < nt) {
                int jj = (tstart + tt) * 16 + frow;
                int dj = jj - r, j = j0 + jj;
                if (dj >= 1 && dj <= 255 && j >= 0 && j < S_LEN) m = fmaxf(m, acc[tt][e]);
            }
        }
        #pragma unroll
        for (int d = 1; d < 16; d <<= 1) m = fmaxf(m, __shfl_xor(m, d));
        if (frow == 0) sred_max[r * 4 + q] = m;
    }
    __syncthreads();
    float sh[4];
    #pragma unroll
    for (int e = 0; e < 4; ++e) {
        int r = g * 16 + rq + e;
        float mx = fmaxf(fmaxf(sred_max[r * 4], sred_max[r * 4 + 1]),
                         fmaxf(sred_max[r * 4 + 2], sred_max[r * 4 + 3]));
        float s = 0.f;
        #pragma unroll
        for (int tt = 0; tt < 5; ++tt) {
            float pv = 0.f;
            if (tt < nt) {
                int jj = (tstart + tt) * 16 + frow;
                int dj = jj - r, j = j0 + jj;
                bool valid = (dj >= 1 && dj <= 255 && j >= 0 && j < S_LEN);
                pv = valid ? __expf(acc[tt][e] - mx) : 0.f;
            }
            acc[tt][e] = pv;
            s += pv;
        }
        #pragma unroll
        for (int d = 1; d < 16; d <<= 1) s += __shfl_xor(s, d);
        sh[e] = s;
    }
    if (frow == 0) {
        #pragma unroll
        for (int e = 0; e < 4; ++e) sred_sum[(g * 16 + rq + e) * 4 + q] = sh[e];
    }
    __syncthreads();
    float invv[4];
    #pragma unroll
    for (int e = 0; e < 4; ++e) {
        int r = g * 16 + rq + e;
        invv[e] = 1.f / (sred_sum[r * 4] + sred_sum[r * 4 + 1] +
                         sred_sum[r * 4 + 2] + sred_sum[r * 4 + 3]);
    }
    __syncthreads();                                 // stats consumed before VL writes
    // write normalized P into PL = smem[0..20480)
    #pragma unroll
    for (int tt = 0; tt < 5; ++tt) {
        if (tt < nt) {
            int t = tstart + tt;
            #pragma unroll
            for (int e = 0; e < 4; ++e) {
                int r = g * 16 + rq + e;
                smem[swz320(r, t * 16 + frow)] = f2bf(acc[tt][e] * invv[e]);
            }
        }
    }
    // band-complement zero-fill: tiles [0,g) by q0, tiles [g+17,20) by q3
    if (q == 0) {
        for (int t = 0; t < g; ++t)
            #pragma unroll
            for (int e = 0; e < 4; ++e)
                smem[swz320(g * 16 + rq + e, t * 16 + frow)] = 0;
    }
    if (q == 3) {
        for (int t = g + 17; t < 20; ++t)
            #pragma unroll
            for (int e = 0; e < 4; ++e)
                smem[swz320(g * 16 + rq + e, t * 16 + frow)] = 0;
    }

    // ---- PV: 8 d-steps of 64 d-rows, reg-staged V into VL ----
    s16x8 vreg[3];
    auto vload = [&](int ds) {
        const int d0 = ds * 64;
        #pragma unroll
        for (int i = 0; i < 3; ++i) {
            int f = i * 1024 + tid;                  // 2560 chunks (64 rows x 40)
            if (f < 2560) {
                int dr = f / 40, c8 = f - dr * 40;
                int jb = j0 + c8 * 8;
                jb = min(max(jb, 0), S_LEN - 8);     // clamped chunks have P==0
                vreg[i] = *(const s16x8*)&xT[(size_t)(b * 512 + d0 + dr) * S_LEN + jb];
            }
        }
    };
    auto vwrite = [&]() {
        #pragma unroll
        for (int i = 0; i < 3; ++i) {
            int f = i * 1024 + tid;
            if (f < 2560) {
                int dr = f / 40, c8 = f - dr * 40;
                *(s16x8*)&smem[20480 + swz320(dr, c8 * 8)] = vreg[i];
            }
        }
    };
    vload(0);
    for (int ds = 0; ds < 8; ++ds) {
        __syncthreads();                 // PL ready (ds=0) / prev VL reads done
        vwrite();
        __syncthreads();                 // VL visible
        if (ds < 7) vload(ds + 1);       // flies under this step's MFMA
        f32x4 po = {};
        __builtin_amdgcn_s_setprio(1);
        #pragma unroll
        for (int jt = 0; jt < 10; ++jt) {
            s16x8 a = *(const s16x8*)&smem[swz320(g * 16 + frow, jt * 32 + fk)];
            s16x8 bv = *(const s16x8*)&smem[20480 + swz320(q * 16 + frow, jt * 32 + fk)];
            po = __builtin_amdgcn_mfma_f32_16x16x32_bf16(a, bv, po, 0, 0, 0);
        }
        __builtin_amdgcn_s_setprio(0);
        #pragma unroll
        for (int e = 0; e < 4; ++e) {
            int r = mrow0 + g * 16 + rq + e;
            out[(size_t)r * 512 + ds * 64 + q * 16 + frow] = po[e];
        }
    }
}

extern "C" void kernel_launch(void* const* d_in, const int* in_sizes, int n_in,
                              void* d_out, int out_size, void* d_ws, size_t ws_size,
                              hipStream_t stream) {
    const float* x  = (const float*)d_in[0];
    const float* Wq = (const float*)d_in[1];
    const float* bq = (const float*)d_in[2];
    const float* Wk = (const float*)d_in[3];
    const float* bk = (const float*)d_in[4];
    (void)bk;
    float* out = (float*)d_out;

    u16* xh  = (u16*)d_ws;
    u16* xl  = xh + (size_t)8388608;
    u16* zh  = xl + (size_t)8388608;
    u16* zl  = zh + (size_t)8388608;
    u16* Mth = zl + (size_t)8388608;
    u16* Mtl = Mth + (size_t)262144;
    u16* xT  = Mtl + (size_t)262144;
    float* uv = (float*)(xT + (size_t)8388608);

    hipLaunchKernelGGL(prep_kernel, dim3(2312), dim3(256), 0, stream,
                       x, Wk, Wq, bq, xh, xl, xT, Mth, Mtl, uv);
    hipLaunchKernelGGL(z_kernel, dim3(512), dim3(512), 0, stream,
                       xh, xl, Mth, Mtl, uv, zh, zl);
    hipLaunchKernelGGL(attn_kernel, dim3(256), dim3(1024), 0, stream,
                       zh, zl, xh, xl, xT, out);
}

// Round 21
// 115.761 us; speedup vs baseline: 1.2253x; 1.0261x over previous
//
#include <hip/hip_runtime.h>
#include <hip/hip_bf16.h>

#define S_LEN 4096
#define NEG_INF_F (-1e30f)

typedef __attribute__((ext_vector_type(4))) float f32x4;
typedef __attribute__((ext_vector_type(8))) short s16x8;
typedef unsigned short u16;

static __device__ __forceinline__ u16 f2bf(float f) {
    unsigned u = __builtin_bit_cast(unsigned, f);
    unsigned r = u + 0x7FFFu + ((u >> 16) & 1u);
    return (u16)(r >> 16);
}
static __device__ __forceinline__ float bf2f(u16 h) {
    unsigned u = ((unsigned)h) << 16;
    return __builtin_bit_cast(float, u);
}
static __device__ __forceinline__ void split4(const float4 v, ushort4& hi, ushort4& lo) {
    hi.x = f2bf(v.x); lo.x = f2bf(v.x - bf2f(hi.x));
    hi.y = f2bf(v.y); lo.y = f2bf(v.y - bf2f(hi.y));
    hi.z = f2bf(v.z); lo.z = f2bf(v.z - bf2f(hi.z));
    hi.w = f2bf(v.w); lo.w = f2bf(v.w - bf2f(hi.w));
}
static __device__ __forceinline__ void gl_lds16(const void* g, void* l) {
    __builtin_amdgcn_global_load_lds(
        (const __attribute__((address_space(1))) void*)g,
        (__attribute__((address_space(3))) void*)l, 16, 0, 0);
}
// swizzled u16 offset within a [rows][64 u16] LDS tile
static __device__ __forceinline__ int swz64(int row, int col_u16) {
    return row * 64 + (col_u16 ^ ((row & 7) << 3));
}
// swizzled u16 offset within a [rows][32 u16] LDS tile
static __device__ __forceinline__ int swz32(int row, int col_u16) {
    return row * 32 + (col_u16 ^ (((row >> 1) & 3) << 3));
}
// swizzled u16 offset within a [rows][320 u16] LDS tile
static __device__ __forceinline__ int swz320(int row, int col_u16) {
    return row * 320 + (col_u16 ^ ((row & 7) << 3));
}
// XCD-chunked bijective swizzles
static __device__ __forceinline__ int xcd_swz512(int bid) {
    return (bid & 7) * 64 + (bid >> 3);
}
static __device__ __forceinline__ int xcd_swz256(int bid) {
    return (bid & 7) * 32 + (bid >> 3);
}

// ---------------- K0: merged prep = mt (256) + u (8) + split_xt (2048) ----------------
// mt/u blocks FIRST so their serial-latency tail hides under split's HBM stream.
__global__ __launch_bounds__(256) void prep_kernel(
    const float* __restrict__ x, const float* __restrict__ Wk,
    const float* __restrict__ Wq, const float* __restrict__ bq,
    u16* __restrict__ xh, u16* __restrict__ xl, u16* __restrict__ xT,
    u16* __restrict__ Mth, u16* __restrict__ Mtl, float* __restrict__ uvec) {
    __shared__ __align__(16) u16 sm[9216];           // 18432 B: max of the 3 roles
    const int bid = blockIdx.x;
    const int tid = threadIdx.x;

    if (bid < 256) {
        // ---- mt role: Mt = Wk^T @ Wq, 32x32 tiles ----
        const int bm = bid & 15, bn = bid >> 4;
        const int m0 = bm * 32, n0 = bn * 32;
        u16* Ath = sm;                               // [32*72]
        u16* Atl = sm + 2304;
        u16* Bth = sm + 4608;
        u16* Btl = sm + 6912;
        const int lane = tid & 63, w = tid >> 6;
        const int rg = w >> 1, cg = w & 1;
        const int frow = lane & 15, fk = (lane >> 4) * 8;
        f32x4 acc = {};

        for (int h0 = 0; h0 < 512; h0 += 64) {
            #pragma unroll
            for (int i = 0; i < 2; ++i) {
                int idx = i * 256 + tid;             // 512 slots: 64 h x 8 c4
                int h = idx >> 3, c4 = (idx & 7) * 4;
                float4 a = *(const float4*)(Wk + (size_t)(h0 + h) * 512 + m0 + c4);
                ushort4 ahi, alo; split4(a, ahi, alo);
                Ath[(c4 + 0) * 72 + h] = ahi.x; Atl[(c4 + 0) * 72 + h] = alo.x;
                Ath[(c4 + 1) * 72 + h] = ahi.y; Atl[(c4 + 1) * 72 + h] = alo.y;
                Ath[(c4 + 2) * 72 + h] = ahi.z; Atl[(c4 + 2) * 72 + h] = alo.z;
                Ath[(c4 + 3) * 72 + h] = ahi.w; Atl[(c4 + 3) * 72 + h] = alo.w;
                float4 b = *(const float4*)(Wq + (size_t)(h0 + h) * 512 + n0 + c4);
                ushort4 bhi, blo; split4(b, bhi, blo);
                Bth[(c4 + 0) * 72 + h] = bhi.x; Btl[(c4 + 0) * 72 + h] = blo.x;
                Bth[(c4 + 1) * 72 + h] = bhi.y; Btl[(c4 + 1) * 72 + h] = blo.y;
                Bth[(c4 + 2) * 72 + h] = bhi.z; Btl[(c4 + 2) * 72 + h] = blo.z;
                Bth[(c4 + 3) * 72 + h] = bhi.w; Btl[(c4 + 3) * 72 + h] = blo.w;
            }
            __syncthreads();
            #pragma unroll
            for (int kk = 0; kk < 2; ++kk) {
                s16x8 aH = *(const s16x8*)&Ath[(rg * 16 + frow) * 72 + kk * 32 + fk];
                s16x8 aL = *(const s16x8*)&Atl[(rg * 16 + frow) * 72 + kk * 32 + fk];
                s16x8 bH = *(const s16x8*)&Bth[(cg * 16 + frow) * 72 + kk * 32 + fk];
                s16x8 bL = *(const s16x8*)&Btl[(cg * 16 + frow) * 72 + kk * 32 + fk];
                acc = __builtin_amdgcn_mfma_f32_16x16x32_bf16(aH, bH, acc, 0, 0, 0);
                acc = __builtin_amdgcn_mfma_f32_16x16x32_bf16(aH, bL, acc, 0, 0, 0);
                acc = __builtin_amdgcn_mfma_f32_16x16x32_bf16(aL, bH, acc, 0, 0, 0);
            }
            __syncthreads();
        }
        int d1 = n0 + cg * 16 + frow;
        #pragma unroll
        for (int e = 0; e < 4; ++e) {
            int d2 = m0 + rg * 16 + (lane >> 4) * 4 + e;
            float v = acc[e];
            u16 hi = f2bf(v);
            Mth[(size_t)d2 * 512 + d1] = hi;
            Mtl[(size_t)d2 * 512 + d1] = f2bf(v - bf2f(hi));
        }
    } else if (bid < 264) {
        // ---- u role: u = Wk^T @ bq ----
        const int ub = bid - 256;
        float* red = (float*)sm;                     // [4][64]
        const int c = tid & 63, hg = tid >> 6;
        const int d2 = ub * 64 + c;
        float acc = 0.f;
        for (int h = hg; h < 512; h += 4) acc += Wk[(size_t)h * 512 + d2] * bq[h];
        red[hg * 64 + c] = acc;
        __syncthreads();
        if (hg == 0)
            uvec[d2] = red[0 * 64 + c] + red[1 * 64 + c] + red[2 * 64 + c] + red[3 * 64 + c];
    } else {
        // ---- split_xt role ----
        const int sb = bid - 264;
        const int dt = sb & 7, st = (sb >> 3) & 63, b = sb >> 9;
        const int s0 = st * 64, d0 = dt * 64;
        u16 (*T)[74] = (u16(*)[74])sm;               // stride 74 (37 dw, 37%32=5)
        #pragma unroll
        for (int i = 0; i < 4; ++i) {
            int idx = i * 256 + tid;
            int r = idx >> 4, c4 = (idx & 15) * 4;
            float4 v = *(const float4*)(x + (size_t)(b * S_LEN + s0 + r) * 512 + d0 + c4);
            ushort4 hi, lo; split4(v, hi, lo);
            *(ushort4*)(xh + (size_t)(b * S_LEN + s0 + r) * 512 + d0 + c4) = hi;
            *(ushort4*)(xl + (size_t)(b * S_LEN + s0 + r) * 512 + d0 + c4) = lo;
            T[r][c4 + 0] = hi.x;                     // scalar stores (2-way, free)
            T[r][c4 + 1] = hi.y;
            T[r][c4 + 2] = hi.z;
            T[r][c4 + 3] = hi.w;
        }
        __syncthreads();
        {
            // u32 transpose reads: each thread builds TWO d-rows from 8 u32 reads
            const int drp = tid >> 3, sc = tid & 7;  // 32 row-pairs x 8 s-chunks
            s16x8 v0, v1;
            #pragma unroll
            for (int t = 0; t < 8; ++t) {
                unsigned wv = *(const unsigned*)&T[sc * 8 + t][drp * 2];
                v0[t] = (short)(wv & 0xFFFFu);
                v1[t] = (short)(wv >> 16);
            }
            size_t base = (size_t)(b * 512 + d0 + drp * 2) * S_LEN + s0 + sc * 8;
            *(s16x8*)&xT[base] = v0;
            *(s16x8*)&xT[base + S_LEN] = v1;
        }
    }
}

// ---------------- K1: z = x @ Mt^T + u (gl_lds single-buffer, round-13) ----------------
__global__ __launch_bounds__(512) void z_kernel(
    const u16* __restrict__ xh, const u16* __restrict__ xl,
    const u16* __restrict__ Mth, const u16* __restrict__ Mtl,
    const float* __restrict__ u, u16* __restrict__ zh, u16* __restrict__ zl) {
    const int w_ = xcd_swz512((int)blockIdx.x);
    const int bm = w_ >> 2, bn = w_ & 3;
    const int m0 = bm * 128, n0 = bn * 128;
    __shared__ __align__(16) u16 Ah[128 * 64], Al[128 * 64];
    __shared__ __align__(16) u16 Bh[128 * 64], Bl[128 * 64];
    const int tid = threadIdx.x, lane = tid & 63, w = tid >> 6;
    const int rg = w >> 2, cg = w & 3;
    const int frow = lane & 15, fk = (lane >> 4) * 8;
    f32x4 acc[4][2] = {};

    for (int k0 = 0; k0 < 512; k0 += 64) {
        #pragma unroll
        for (int i = 0; i < 2; ++i) {
            int idx = i * 512 + tid;
            int r = idx >> 3, c = idx & 7;
            int sc = (c ^ (r & 7)) * 8;
            gl_lds16(xh + (size_t)(m0 + r) * 512 + k0 + sc, &Ah[idx * 8]);
            gl_lds16(xl + (size_t)(m0 + r) * 512 + k0 + sc, &Al[idx * 8]);
            gl_lds16(Mth + (size_t)(n0 + r) * 512 + k0 + sc, &Bh[idx * 8]);
            gl_lds16(Mtl + (size_t)(n0 + r) * 512 + k0 + sc, &Bl[idx * 8]);
        }
        __syncthreads();
        #pragma unroll
        for (int kk = 0; kk < 2; ++kk) {
            s16x8 aH[4], aL[4], bH[2], bL[2];
            #pragma unroll
            for (int mi = 0; mi < 4; ++mi) {
                int row = rg * 64 + mi * 16 + frow;
                aH[mi] = *(const s16x8*)&Ah[swz64(row, kk * 32 + fk)];
                aL[mi] = *(const s16x8*)&Al[swz64(row, kk * 32 + fk)];
            }
            #pragma unroll
            for (int ni = 0; ni < 2; ++ni) {
                int row = cg * 32 + ni * 16 + frow;
                bH[ni] = *(const s16x8*)&Bh[swz64(row, kk * 32 + fk)];
                bL[ni] = *(const s16x8*)&Bl[swz64(row, kk * 32 + fk)];
            }
            #pragma unroll
            for (int mi = 0; mi < 4; ++mi)
                #pragma unroll
                for (int ni = 0; ni < 2; ++ni) {
                    acc[mi][ni] = __builtin_amdgcn_mfma_f32_16x16x32_bf16(aH[mi], bH[ni], acc[mi][ni], 0, 0, 0);
                    acc[mi][ni] = __builtin_amdgcn_mfma_f32_16x16x32_bf16(aH[mi], bL[ni], acc[mi][ni], 0, 0, 0);
                    acc[mi][ni] = __builtin_amdgcn_mfma_f32_16x16x32_bf16(aL[mi], bH[ni], acc[mi][ni], 0, 0, 0);
                }
        }
        __syncthreads();
    }
    #pragma unroll
    for (int ni = 0; ni < 2; ++ni) {
        int col = n0 + cg * 32 + ni * 16 + frow;
        float uv = u[col];
        #pragma unroll
        for (int mi = 0; mi < 4; ++mi) {
            int rbase = m0 + rg * 64 + mi * 16 + (lane >> 4) * 4;
            #pragma unroll
            for (int e = 0; e < 4; ++e) {
                float v = acc[mi][ni][e] + uv;
                u16 hi = f2bf(v);
                zh[(size_t)(rbase + e) * 512 + col] = hi;
                zl[(size_t)(rbase + e) * 512 + col] = f2bf(v - bf2f(hi));
            }
        }
    }
}

// ---------------- K2: fused banded attention, PV a-frag hoist + VL dbuf ----------------
__global__ __launch_bounds__(1024, 4) void attn_kernel(
    const u16* __restrict__ zh, const u16* __restrict__ zl,
    const u16* __restrict__ xh, const u16* __restrict__ xl,
    const u16* __restrict__ xT, float* __restrict__ out) {
    const int w_ = xcd_swz256((int)blockIdx.x);
    const int b = w_ >> 6, it = w_ & 63;
    const int i0 = it * 64, j0 = i0 - 128;
    const int mrow0 = b * S_LEN + i0;

    __shared__ __align__(16) u16 smem[61440];        // 120 KB
    // QK: buf0 [0,20480), buf1 [20480,40960)  (u16 indices)
    // PV: PL [0,20480); VL0 [20480,40960); VL1 [40960,61440)

    const int tid = threadIdx.x, lane = tid & 63, w = tid >> 6;
    const int g = w >> 2, q = w & 3;
    const int frow = lane & 15, fk = (lane >> 4) * 8;
    const int tstart = g + q * 4;
    const int nt = (q == 3) ? 5 : 4;
    const size_t qoff = (size_t)(mrow0 + g * 16 + frow) * 512;
    const int rq = (lane >> 4) * 4;

    f32x4 acc[5] = {};
    s16x8 krA[3], krB[3];

    auto kload = [&](int s, s16x8* kr) {
        const int k0 = s * 32;
        #pragma unroll
        for (int i = 0; i < 3; ++i) {
            int f = i * 1024 + tid;
            if (f < 2560) {
                int idx = (f < 1280) ? f : f - 1280;
                int r = idx >> 2, c = idx & 3;
                int j = min(max(j0 + r, 0), S_LEN - 1);
                const u16* src = (f < 1280) ? xh : xl;
                kr[i] = *(const s16x8*)(src + (size_t)(b * S_LEN + j) * 512 + k0 + c * 8);
            }
        }
    };
    auto kwrite = [&](const s16x8* kr, int bufoff) {
        #pragma unroll
        for (int i = 0; i < 3; ++i) {
            int f = i * 1024 + tid;
            if (f < 2560) {
                int idx = (f < 1280) ? f : f - 1280;
                int r = idx >> 2, c = idx & 3;
                int off = bufoff + ((f < 1280) ? 0 : 10240) + swz32(r, c * 8);
                *(s16x8*)&smem[off] = kr[i];
            }
        }
    };
    auto qkstep = [&](int t, int bufoff) {
        const int k0 = t * 32;
        s16x8 zH = *(const s16x8*)(zh + qoff + k0 + fk);
        s16x8 zL = *(const s16x8*)(zl + qoff + k0 + fk);
        __builtin_amdgcn_s_setprio(1);
        #pragma unroll
        for (int tt = 0; tt < 5; ++tt) {
            if (tt < nt) {
                int krow = (tstart + tt) * 16 + frow;
                s16x8 bH = *(const s16x8*)&smem[bufoff + swz32(krow, fk)];
                s16x8 bL = *(const s16x8*)&smem[bufoff + 10240 + swz32(krow, fk)];
                acc[tt] = __builtin_amdgcn_mfma_f32_16x16x32_bf16(zH, bH, acc[tt], 0, 0, 0);
                acc[tt] = __builtin_amdgcn_mfma_f32_16x16x32_bf16(zH, bL, acc[tt], 0, 0, 0);
                acc[tt] = __builtin_amdgcn_mfma_f32_16x16x32_bf16(zL, bH, acc[tt], 0, 0, 0);
            }
        }
        __builtin_amdgcn_s_setprio(0);
    };

    // ---- QK^T: 16 steps, dbuf, reg-staged ----
    kload(0, krA);
    kwrite(krA, 0);
    kload(1, krB);
    __syncthreads();
    for (int tt2 = 0; tt2 < 16; tt2 += 2) {
        if (tt2 + 1 < 16) kwrite(krB, 20480);
        if (tt2 + 2 < 16) kload(tt2 + 2, krA);
        qkstep(tt2, 0);
        __syncthreads();
        if (tt2 + 1 < 16) {
            if (tt2 + 2 < 16) kwrite(krA, 0);
            if (tt2 + 3 < 16) kload(tt2 + 3, krB);
            qkstep(tt2 + 1, 20480);
            __syncthreads();
        }
    }

    // ---- PV V staging lambdas (declared early so vload(0) can overlap softmax) ----
    s16x8 vreg[3];
    auto vload = [&](int ds) {
        const int d0 = ds * 64;
        #pragma unroll
        for (int i = 0; i < 3; ++i) {
            int f = i * 1024 + tid;                  // 2560 chunks (64 rows x 40)
            if (f < 2560) {
                int dr = f / 40, c8 = f - dr * 40;
                int jb = j0 + c8 * 8;
                jb = min(max(jb, 0), S_LEN - 8);     // clamped chunks have P==0
                vreg[i] = *(const s16x8*)&xT[(size_t)(b * 512 + d0 + dr) * S_LEN + jb];
            }
        }
    };
    auto vwrite = [&](int vbase) {
        #pragma unroll
        for (int i = 0; i < 3; ++i) {
            int f = i * 1024 + tid;
            if (f < 2560) {
                int dr = f / 40, c8 = f - dr * 40;
                *(s16x8*)&smem[vbase + swz320(dr, c8 * 8)] = vreg[i];
            }
        }
    };
    vload(0);

    // ---- softmax (stats alias VL0 region; consumed before first vwrite) ----
    float* sred_max = (float*)&smem[20480];          // [64][4]
    float* sred_sum = sred_max + 256;                // [64][4]
    #pragma unroll
    for (int e = 0; e < 4; ++e) {
        int r = g * 16 + rq + e;
        float m = NEG_INF_F;
        #pragma unroll
        for (int tt = 0; tt < 5; ++tt) {
            if (tt < nt) {
                int jj = (tstart + tt) * 16 + frow;
                int dj = jj - r, j = j0 + jj;
                if (dj >= 1 && dj <= 255 && j >= 0 && j < S_LEN) m = fmaxf(m, acc[tt][e]);
            }
        }
        #pragma unroll
        for (int d = 1; d < 16; d <<= 1) m = fmaxf(m, __shfl_xor(m, d));
        if (frow == 0) sred_max[r * 4 + q] = m;
    }
    __syncthreads();
    float sh[4];
    #pragma unroll
    for (int e = 0; e < 4; ++e) {
        int r = g * 16 + rq + e;
        float mx = fmaxf(fmaxf(sred_max[r * 4], sred_max[r * 4 + 1]),
                         fmaxf(sred_max[r * 4 + 2], sred_max[r * 4 + 3]));
        float s = 0.f;
        #pragma unroll
        for (int tt = 0; tt < 5; ++tt) {
            float pv = 0.f;
            if (tt < nt) {
                int jj = (tstart + tt) * 16 + frow;
                int dj = jj - r, j = j0 + jj;
                bool valid = (dj >= 1 && dj <= 255 && j >= 0 && j < S_LEN);
                pv = valid ? __expf(acc[tt][e] - mx) : 0.f;
            }
            acc[tt][e] = pv;
            s += pv;
        }
        #pragma unroll
        for (int d = 1; d < 16; d <<= 1) s += __shfl_xor(s, d);
        sh[e] = s;
    }
    if (frow == 0) {
        #pragma unroll
        for (int e = 0; e < 4; ++e) sred_sum[(g * 16 + rq + e) * 4 + q] = sh[e];
    }
    __syncthreads();
    float invv[4];
    #pragma unroll
    for (int e = 0; e < 4; ++e) {
        int r = g * 16 + rq + e;
        invv[e] = 1.f / (sred_sum[r * 4] + sred_sum[r * 4 + 1] +
                         sred_sum[r * 4 + 2] + sred_sum[r * 4 + 3]);
    }
    __syncthreads();                                 // stats consumed
    // write normalized P into PL = smem[0..20480)
    #pragma unroll
    for (int tt = 0; tt < 5; ++tt) {
        if (tt < nt) {
            int t = tstart + tt;
            #pragma unroll
            for (int e = 0; e < 4; ++e) {
                int r = g * 16 + rq + e;
                smem[swz320(r, t * 16 + frow)] = f2bf(acc[tt][e] * invv[e]);
            }
        }
    }
    // band-complement zero-fill: tiles [0,g) by q0, tiles [g+17,20) by q3
    if (q == 0) {
        for (int t = 0; t < g; ++t)
            #pragma unroll
            for (int e = 0; e < 4; ++e)
                smem[swz320(g * 16 + rq + e, t * 16 + frow)] = 0;
    }
    if (q == 3) {
        for (int t = g + 17; t < 20; ++t)
            #pragma unroll
            for (int e = 0; e < 4; ++e)
                smem[swz320(g * 16 + rq + e, t * 16 + frow)] = 0;
    }
    __syncthreads();                                 // PL ready; stats dead

    // ---- PV prologue: fill VL0, prefetch step 1 ----
    vwrite(20480);                                   // vreg(0) -> VL0
    vload(1);
    __syncthreads();                                 // VL0 visible

    // hoist P A-frags (ds-invariant) to registers
    s16x8 afrag[10];
    #pragma unroll
    for (int jt = 0; jt < 10; ++jt)
        afrag[jt] = *(const s16x8*)&smem[swz320(g * 16 + frow, jt * 32 + fk)];

    // ---- PV: 8 d-steps, VL double-buffered, ONE barrier per step ----
    for (int ds = 0; ds < 8; ++ds) {
        const int cur = 20480 + (ds & 1) * 20480;
        const int nxt = 20480 + ((ds + 1) & 1) * 20480;
        if (ds < 7) {
            vwrite(nxt);                 // vreg holds ds+1 data
            if (ds < 6) vload(ds + 2);   // flies under this step's MFMA
        }
        f32x4 po = {};
        __builtin_amdgcn_s_setprio(1);
        #pragma unroll
        for (int jt = 0; jt < 10; ++jt) {
            s16x8 bv = *(const s16x8*)&smem[cur + swz320(q * 16 + frow, jt * 32 + fk)];
            po = __builtin_amdgcn_mfma_f32_16x16x32_bf16(afrag[jt], bv, po, 0, 0, 0);
        }
        __builtin_amdgcn_s_setprio(0);
        #pragma unroll
        for (int e = 0; e < 4; ++e) {
            int r = mrow0 + g * 16 + rq + e;
            out[(size_t)r * 512 + ds * 64 + q * 16 + frow] = po[e];
        }
        __syncthreads();
    }
}

extern "C" void kernel_launch(void* const* d_in, const int* in_sizes, int n_in,
                              void* d_out, int out_size, void* d_ws, size_t ws_size,
                              hipStream_t stream) {
    const float* x  = (const float*)d_in[0];
    const float* Wq = (const float*)d_in[1];
    const float* bq = (const float*)d_in[2];
    const float* Wk = (const float*)d_in[3];
    const float* bk = (const float*)d_in[4];
    (void)bk;
    float* out = (float*)d_out;

    u16* xh  = (u16*)d_ws;
    u16* xl  = xh + (size_t)8388608;
    u16* zh  = xl + (size_t)8388608;
    u16* zl  = zh + (size_t)8388608;
    u16* Mth = zl + (size_t)8388608;
    u16* Mtl = Mth + (size_t)262144;
    u16* xT  = Mtl + (size_t)262144;
    float* uv = (float*)(xT + (size_t)8388608);

    hipLaunchKernelGGL(prep_kernel, dim3(2312), dim3(256), 0, stream,
                       x, Wk, Wq, bq, xh, xl, xT, Mth, Mtl, uv);
    hipLaunchKernelGGL(z_kernel, dim3(512), dim3(512), 0, stream,
                       xh, xl, Mth, Mtl, uv, zh, zl);
    hipLaunchKernelGGL(attn_kernel, dim3(256), dim3(1024), 0, stream,
                       zh, zl, xh, xl, xT, out);
}